// Round 9
// baseline (359.486 us; speedup 1.0000x reference)
//
#include <hip/hip_runtime.h>
#include <hip/hip_bf16.h>
#include <hip/hip_fp16.h>

#define HID 128
#define NCLS 16
#define NGRAPH 64

using bf16x8 = __attribute__((ext_vector_type(8))) short;
using f32x4  = __attribute__((ext_vector_type(4))) float;

// round-to-nearest-even f32 -> bf16
__device__ __forceinline__ unsigned int f2bf(float f) {
    unsigned int u = __float_as_uint(f);
    return (u + 0x7FFFu + ((u >> 16) & 1u)) >> 16;
}
__device__ __forceinline__ float bf2f_lo(unsigned int u) { return __uint_as_float(u << 16); }
__device__ __forceinline__ float bf2f_hi(unsigned int u) { return __uint_as_float(u & 0xFFFF0000u); }

// ---------------- init: zero counts/pooled + W0/W1 transpose-bf16 + W2@Wc fold ----------------
__global__ __launch_bounds__(256) void k_init(int* counts, float* pooled,
                                              const float* __restrict__ W0,
                                              const float* __restrict__ W1,
                                              const float* __restrict__ W2,
                                              const float* __restrict__ Wc,
                                              const float* __restrict__ b2,
                                              const float* __restrict__ bcin,
                                              unsigned short* __restrict__ Wt,
                                              unsigned short* __restrict__ Wt2c,
                                              float* __restrict__ bc2, int n) {
    int i = blockIdx.x * 256 + threadIdx.x;
    if (i < n) counts[i] = 0;
    if (i < NGRAPH * NCLS) pooled[i] = 0.0f;
    if (i < 2 * HID * HID) {           // Wt[m][col*128+k] = bf16(W[m][k*128+col])
        int m = i >> 14;
        int r = i & 16383;
        int c = r >> 7, k = r & 127;
        const float* W = (m == 0) ? W0 : W1;
        Wt[i] = (unsigned short)f2bf(W[k * HID + c]);
    }
    if (i < HID * NCLS) {              // Wt2c[c*128+k] = bf16(sum_j W2[k,j]*Wc[j,c])
        int k = i >> 4, c = i & 15;
        float s = 0.f;
        #pragma unroll 8
        for (int j = 0; j < HID; ++j)
            s = fmaf(W2[k * HID + j], Wc[j * NCLS + c], s);
        Wt2c[c * 128 + k] = (unsigned short)f2bf(s);
    }
    if (i < NCLS) {                    // bc2 = b2@Wc + bc
        float s = 0.f;
        for (int j = 0; j < HID; ++j)
            s = fmaf(b2[j], Wc[j * NCLS + i], s);
        bc2[i] = s + bcin[i];
    }
}

// ---------------- degree histogram over dst + per-edge rank ----------------
__global__ __launch_bounds__(256) void k_hist(const int* __restrict__ dst,
                                              int* counts, int* rank, int e) {
    int i = blockIdx.x * 256 + threadIdx.x;
    if (i < e) rank[i] = atomicAdd(&counts[dst[i]], 1);
}

// ---------------- rowptr: single-block 1024-thread exclusive scan of counts ----------------
__global__ __launch_bounds__(1024) void k_scan(const int* __restrict__ counts,
                                               int* rowptr, int n, int e) {
    __shared__ int sc[1024];
    int t = threadIdx.x;
    int per = (n + 1023) >> 10;
    int base = t * per;
    int s = 0;
    for (int j = 0; j < per; ++j) { int i = base + j; if (i < n) s += counts[i]; }
    sc[t] = s; __syncthreads();
    for (int off = 1; off < 1024; off <<= 1) {
        int x = sc[t];
        int y = (t >= off) ? sc[t - off] : 0;
        __syncthreads();
        sc[t] = x + y;
        __syncthreads();
    }
    int run = sc[t] - s;               // exclusive prefix
    for (int j = 0; j < per; ++j) {
        int i = base + j;
        if (i < n) { rowptr[i] = run; run += counts[i]; }
    }
    if (t == 0) rowptr[n] = e;
}

// ---------------- CSR fill: 4B records {u16 src | fp16 norm}, no atomics ----------------
__global__ __launch_bounds__(256) void k_fill(const int* __restrict__ src,
                                              const int* __restrict__ dst,
                                              const int* __restrict__ rank,
                                              const int* __restrict__ counts,
                                              const int* __restrict__ rowptr,
                                              unsigned int* __restrict__ epk, int e) {
    int i = blockIdx.x * 256 + threadIdx.x;
    if (i >= e) return;
    int s = src[i], d = dst[i];
    int pos = rowptr[d] + rank[i];
    float norm = rsqrtf((float)(counts[s] + 1)) * rsqrtf((float)(counts[d] + 1));
    __half h = __float2half(norm);
    unsigned int hu = (unsigned int)__half_as_ushort(h);
    epk[pos] = (unsigned int)s | (hu << 16);
}

// ---------------- MFMA GEMM (f32 input, layer 0) ----------------
__global__ __launch_bounds__(256) void k_gemm_f32(const float* __restrict__ H,
                                                  const unsigned short* __restrict__ Wt,
                                                  unsigned short* __restrict__ Tb16, int n) {
    __shared__ char ldsA[64 * 256];
    int t = threadIdx.x;
    int cg = t & 31;
    int rg = t >> 5;
    int row0 = blockIdx.x * 64;

    #pragma unroll
    for (int i = 0; i < 8; ++i) {
        int lr = rg + i * 8;
        int r = row0 + lr;
        float4 v = make_float4(0.f, 0.f, 0.f, 0.f);
        if (r < n) v = ((const float4*)H)[(size_t)r * 32 + cg];
        uint2 pk;
        pk.x = f2bf(v.x) | (f2bf(v.y) << 16);
        pk.y = f2bf(v.z) | (f2bf(v.w) << 16);
        int byte = lr * 256 + cg * 8;
        *(uint2*)(ldsA + (byte ^ ((lr & 7) << 4))) = pk;
    }
    __syncthreads();

    int lane = t & 63;
    int w = t >> 6;
    int rsub = lane & 15;
    int kg = lane >> 4;
    int rowIdx = w * 16 + rsub;
    int abase = rowIdx * 256 + kg * 16;
    int aswz = (rowIdx & 7) << 4;

    f32x4 acc[8];
    #pragma unroll
    for (int nt = 0; nt < 8; ++nt) acc[nt] = (f32x4)(0.f);

    #pragma unroll
    for (int kk = 0; kk < 4; ++kk) {
        bf16x8 a = *(const bf16x8*)(ldsA + ((abase + kk * 64) ^ aswz));
        int k0 = kk * 32 + kg * 8;
        #pragma unroll
        for (int nt = 0; nt < 8; ++nt) {
            int col = nt * 16 + rsub;
            bf16x8 b = *(const bf16x8*)(Wt + col * 128 + k0);
            acc[nt] = __builtin_amdgcn_mfma_f32_16x16x32_bf16(a, b, acc[nt], 0, 0, 0);
        }
    }

    // C/D layout: col = lane&15, row = (lane>>4)*4 + reg
    #pragma unroll
    for (int nt = 0; nt < 8; ++nt) {
        #pragma unroll
        for (int j = 0; j < 4; ++j) {
            int row = row0 + w * 16 + kg * 4 + j;
            int col = nt * 16 + rsub;
            if (row < n) Tb16[(size_t)row * 128 + col] = (unsigned short)f2bf(acc[nt][j]);
        }
    }
}

// ---------------- MFMA GEMM (bf16 input, layer 1) ----------------
__global__ __launch_bounds__(256) void k_gemm_bf16(const unsigned short* __restrict__ Hb,
                                                   const unsigned short* __restrict__ Wt,
                                                   unsigned short* __restrict__ Tb16, int n) {
    __shared__ char ldsA[64 * 256];
    int t = threadIdx.x;
    int row0 = blockIdx.x * 64;
    int c16 = t & 15;
    int rbase = t >> 4;

    #pragma unroll
    for (int i = 0; i < 4; ++i) {
        int lr = rbase + i * 16;
        int r = row0 + lr;
        uint4 v = make_uint4(0u, 0u, 0u, 0u);
        if (r < n) v = *(const uint4*)(Hb + (size_t)r * 128 + c16 * 8);
        int byte = lr * 256 + c16 * 16;
        *(uint4*)(ldsA + (byte ^ ((lr & 7) << 4))) = v;
    }
    __syncthreads();

    int lane = t & 63;
    int w = t >> 6;
    int rsub = lane & 15;
    int kg = lane >> 4;
    int rowIdx = w * 16 + rsub;
    int abase = rowIdx * 256 + kg * 16;
    int aswz = (rowIdx & 7) << 4;

    f32x4 acc[8];
    #pragma unroll
    for (int nt = 0; nt < 8; ++nt) acc[nt] = (f32x4)(0.f);

    #pragma unroll
    for (int kk = 0; kk < 4; ++kk) {
        bf16x8 a = *(const bf16x8*)(ldsA + ((abase + kk * 64) ^ aswz));
        int k0 = kk * 32 + kg * 8;
        #pragma unroll
        for (int nt = 0; nt < 8; ++nt) {
            int col = nt * 16 + rsub;
            bf16x8 b = *(const bf16x8*)(Wt + col * 128 + k0);
            acc[nt] = __builtin_amdgcn_mfma_f32_16x16x32_bf16(a, b, acc[nt], 0, 0, 0);
        }
    }

    #pragma unroll
    for (int nt = 0; nt < 8; ++nt) {
        #pragma unroll
        for (int j = 0; j < 4; ++j) {
            int row = row0 + w * 16 + kg * 4 + j;
            int col = nt * 16 + rsub;
            if (row < n) Tb16[(size_t)row * 128 + col] = (unsigned short)f2bf(acc[nt][j]);
        }
    }
}

// ---------------- agg layer 0: bf16 gather, f32 acc -> relu bf16 out ----------------
__global__ __launch_bounds__(256) void k_agg(const unsigned int* __restrict__ Tb,
                                             unsigned int* __restrict__ outB,
                                             const int* __restrict__ rowptr,
                                             const unsigned int* __restrict__ epk,
                                             const float* __restrict__ bias, int n) {
    int wid = (blockIdx.x * 256 + threadIdx.x) >> 6;
    int lane = threadIdx.x & 63;
    if (wid >= n) return;
    float2 b2 = ((const float2*)bias)[lane];
    unsigned int us = Tb[(size_t)wid * 64 + lane];
    int start = rowptr[wid];
    int deg = rowptr[wid + 1] - start;
    float sn = 1.0f / (float)(deg + 1);
    float2 acc;
    acc.x = fmaf(bf2f_lo(us), sn, b2.x);
    acc.y = fmaf(bf2f_hi(us), sn, b2.y);

    for (int j0 = 0; j0 < deg; j0 += 64) {
        int myj = j0 + lane;
        unsigned int rec = 0;
        if (myj < deg) rec = epk[start + myj];
        int m = min(64, deg - j0);
        int jj = 0;
        for (; jj + 16 <= m; jj += 16) {
            unsigned int rr[16], uu[16];
            #pragma unroll
            for (int k = 0; k < 16; ++k) rr[k] = (unsigned int)__shfl((int)rec, jj + k);
            #pragma unroll
            for (int k = 0; k < 16; ++k) uu[k] = Tb[(size_t)(rr[k] & 0xFFFFu) * 64 + lane];
            #pragma unroll
            for (int k = 0; k < 16; ++k) {
                float wk = __half2float(__ushort_as_half((unsigned short)(rr[k] >> 16)));
                acc.x = fmaf(wk, bf2f_lo(uu[k]), acc.x);
                acc.y = fmaf(wk, bf2f_hi(uu[k]), acc.y);
            }
        }
        for (; jj + 4 <= m; jj += 4) {
            unsigned int rr[4], uu[4];
            #pragma unroll
            for (int k = 0; k < 4; ++k) rr[k] = (unsigned int)__shfl((int)rec, jj + k);
            #pragma unroll
            for (int k = 0; k < 4; ++k) uu[k] = Tb[(size_t)(rr[k] & 0xFFFFu) * 64 + lane];
            #pragma unroll
            for (int k = 0; k < 4; ++k) {
                float wk = __half2float(__ushort_as_half((unsigned short)(rr[k] >> 16)));
                acc.x = fmaf(wk, bf2f_lo(uu[k]), acc.x);
                acc.y = fmaf(wk, bf2f_hi(uu[k]), acc.y);
            }
        }
        for (; jj < m; ++jj) {
            unsigned int rj = (unsigned int)__shfl((int)rec, jj);
            unsigned int u = Tb[(size_t)(rj & 0xFFFFu) * 64 + lane];
            float wj = __half2float(__ushort_as_half((unsigned short)(rj >> 16)));
            acc.x = fmaf(wj, bf2f_lo(u), acc.x);
            acc.y = fmaf(wj, bf2f_hi(u), acc.y);
        }
    }

    float rx = fmaxf(acc.x, 0.f), ry = fmaxf(acc.y, 0.f);
    outB[(size_t)wid * 64 + lane] = f2bf(rx) | (f2bf(ry) << 16);
}

// ---------------- agg layer 1 FUSED with 16-wide GEMM (W2@Wc): T16[wid] = relu_bf16(agg) . W2c ----------------
// After the gather, round h to bf16 pairs (matches unfused numerics), stage in
// LDS per-wave, dot with per-lane register-cached W2c slice, combine via shfl.
__global__ __launch_bounds__(256) void k_agg_fused(const unsigned int* __restrict__ Tb,
                                                   float* __restrict__ T16,
                                                   const int* __restrict__ rowptr,
                                                   const unsigned int* __restrict__ epk,
                                                   const float* __restrict__ bias,
                                                   const unsigned short* __restrict__ Wt2c,
                                                   int n) {
    __shared__ unsigned int sh[4][64];
    int t = threadIdx.x;
    int wid = (blockIdx.x * 256 + t) >> 6;
    int lane = t & 63;
    int w = t >> 6;
    int c = lane & 15;            // output class
    int half = lane >> 4;         // k-quarter 0..3 (features half*32 .. +31)
    bool valid = wid < n;

    // preload W2c slice: u32 idx c*64 + half*16 + kk, kk=0..15 (64B contiguous)
    const uint4* wq = (const uint4*)((const unsigned int*)Wt2c + (c * 64 + half * 16));
    uint4 wv0 = wq[0], wv1 = wq[1], wv2 = wq[2], wv3 = wq[3];
    unsigned int wreg[16] = { wv0.x, wv0.y, wv0.z, wv0.w, wv1.x, wv1.y, wv1.z, wv1.w,
                              wv2.x, wv2.y, wv2.z, wv2.w, wv3.x, wv3.y, wv3.z, wv3.w };

    float2 acc = make_float2(0.f, 0.f);
    int start = 0, deg = 0;
    if (valid) {
        float2 b2 = ((const float2*)bias)[lane];
        unsigned int us = Tb[(size_t)wid * 64 + lane];
        start = rowptr[wid];
        deg = rowptr[wid + 1] - start;
        float sn = 1.0f / (float)(deg + 1);
        acc.x = fmaf(bf2f_lo(us), sn, b2.x);
        acc.y = fmaf(bf2f_hi(us), sn, b2.y);
    }

    for (int j0 = 0; j0 < deg; j0 += 64) {
        int myj = j0 + lane;
        unsigned int rec = 0;
        if (myj < deg) rec = epk[start + myj];
        int m = min(64, deg - j0);
        int jj = 0;
        for (; jj + 16 <= m; jj += 16) {
            unsigned int rr[16], uu[16];
            #pragma unroll
            for (int k = 0; k < 16; ++k) rr[k] = (unsigned int)__shfl((int)rec, jj + k);
            #pragma unroll
            for (int k = 0; k < 16; ++k) uu[k] = Tb[(size_t)(rr[k] & 0xFFFFu) * 64 + lane];
            #pragma unroll
            for (int k = 0; k < 16; ++k) {
                float wk = __half2float(__ushort_as_half((unsigned short)(rr[k] >> 16)));
                acc.x = fmaf(wk, bf2f_lo(uu[k]), acc.x);
                acc.y = fmaf(wk, bf2f_hi(uu[k]), acc.y);
            }
        }
        for (; jj + 4 <= m; jj += 4) {
            unsigned int rr[4], uu[4];
            #pragma unroll
            for (int k = 0; k < 4; ++k) rr[k] = (unsigned int)__shfl((int)rec, jj + k);
            #pragma unroll
            for (int k = 0; k < 4; ++k) uu[k] = Tb[(size_t)(rr[k] & 0xFFFFu) * 64 + lane];
            #pragma unroll
            for (int k = 0; k < 4; ++k) {
                float wk = __half2float(__ushort_as_half((unsigned short)(rr[k] >> 16)));
                acc.x = fmaf(wk, bf2f_lo(uu[k]), acc.x);
                acc.y = fmaf(wk, bf2f_hi(uu[k]), acc.y);
            }
        }
        for (; jj < m; ++jj) {
            unsigned int rj = (unsigned int)__shfl((int)rec, jj);
            unsigned int u = Tb[(size_t)(rj & 0xFFFFu) * 64 + lane];
            float wj = __half2float(__ushort_as_half((unsigned short)(rj >> 16)));
            acc.x = fmaf(wj, bf2f_lo(u), acc.x);
            acc.y = fmaf(wj, bf2f_hi(u), acc.y);
        }
    }

    // relu + bf16-round (same values the unfused path stored), stage per-wave
    float rx = fmaxf(acc.x, 0.f), ry = fmaxf(acc.y, 0.f);
    sh[w][lane] = f2bf(rx) | (f2bf(ry) << 16);
    __syncthreads();

    // dot: part = sum over this lane's 16 h-pairs
    float part = 0.f;
    #pragma unroll
    for (int kk = 0; kk < 16; ++kk) {
        unsigned int hu = sh[w][half * 16 + kk];   // broadcast across the 16 c-lanes
        unsigned int wu = wreg[kk];
        part = fmaf(bf2f_lo(hu), bf2f_lo(wu), part);
        part = fmaf(bf2f_hi(hu), bf2f_hi(wu), part);
    }
    part += __shfl_xor(part, 16);
    part += __shfl_xor(part, 32);

    if (valid && half == 0) T16[(size_t)wid * 16 + c] = part;
}

// ---------------- agg16 + pool FUSED: gather T16 (L2-resident), atomicAdd into pooled ----------------
__global__ __launch_bounds__(256) void k_agg16pool(const float* __restrict__ T16,
                                                   float* __restrict__ pooled,
                                                   const int* __restrict__ rowptr,
                                                   const unsigned int* __restrict__ epk,
                                                   const int* __restrict__ batch, int n) {
    int wid = (blockIdx.x * 256 + threadIdx.x) >> 6;
    int lane = threadIdx.x & 63;
    if (wid >= n) return;
    int p = lane & 15;
    int q = lane >> 4;
    int start = rowptr[wid];
    int deg = rowptr[wid + 1] - start;

    float acc = 0.f;
    if (q == 0) {
        float sn = 1.0f / (float)(deg + 1);
        acc = T16[(size_t)wid * 16 + p] * sn;
    }

    for (int j0 = 0; j0 < deg; j0 += 64) {
        int myj = j0 + lane;
        unsigned int rec = 0;
        if (myj < deg) rec = epk[start + myj];
        int m = min(64, deg - j0);
        int mg = (m - q + 3) >> 2;
        int jj = 0;
        for (; jj + 8 <= mg; jj += 8) {
            unsigned int rr[8]; float uu[8];
            #pragma unroll
            for (int k = 0; k < 8; ++k) rr[k] = (unsigned int)__shfl((int)rec, 4 * (jj + k) + q);
            #pragma unroll
            for (int k = 0; k < 8; ++k) uu[k] = T16[(size_t)(rr[k] & 0xFFFFu) * 16 + p];
            #pragma unroll
            for (int k = 0; k < 8; ++k) {
                float wk = __half2float(__ushort_as_half((unsigned short)(rr[k] >> 16)));
                acc = fmaf(wk, uu[k], acc);
            }
        }
        for (; jj < mg; ++jj) {
            unsigned int rj = (unsigned int)__shfl((int)rec, 4 * jj + q);
            float u = T16[(size_t)(rj & 0xFFFFu) * 16 + p];
            float wj = __half2float(__ushort_as_half((unsigned short)(rj >> 16)));
            acc = fmaf(wj, u, acc);
        }
    }

    acc += __shfl_xor(acc, 16);
    acc += __shfl_xor(acc, 32);

    if (q == 0) atomicAdd(&pooled[batch[wid] * NCLS + p], acc);
}

// ---------------- head: out[g,c] = pooled[g,c]/cnt(g) + bc2[c]; cnt via bsearch on sorted batch ----------------
__global__ __launch_bounds__(256) void k_head16(const float* __restrict__ pooled,
                                                const int* __restrict__ batch,
                                                const float* __restrict__ bc2,
                                                float* __restrict__ out, int n) {
    int idx = blockIdx.x * 256 + threadIdx.x;
    if (idx >= NGRAPH * NCLS) return;
    int g = idx >> 4, c = idx & 15;
    // lower_bound(g) and lower_bound(g+1)
    int lo = 0, hi = n;
    while (lo < hi) { int mid = (lo + hi) >> 1; if (batch[mid] < g) lo = mid + 1; else hi = mid; }
    int lb = lo;
    lo = 0; hi = n;
    while (lo < hi) { int mid = (lo + hi) >> 1; if (batch[mid] < g + 1) lo = mid + 1; else hi = mid; }
    float cnt = (float)(lo - lb);
    float inv = 1.0f / fmaxf(cnt, 1.0f);
    out[idx] = pooled[idx] * inv + bc2[c];
}

extern "C" void kernel_launch(void* const* d_in, const int* in_sizes, int n_in,
                              void* d_out, int out_size, void* d_ws, size_t ws_size,
                              hipStream_t stream) {
    const float* x    = (const float*)d_in[0];
    const int*   ei   = (const int*)d_in[1];
    const int*   batch= (const int*)d_in[2];
    const float* W0   = (const float*)d_in[3];
    const float* b0   = (const float*)d_in[4];
    const float* W1   = (const float*)d_in[5];
    const float* b1   = (const float*)d_in[6];
    const float* W2   = (const float*)d_in[7];
    const float* b2   = (const float*)d_in[8];
    const float* Wc   = (const float*)d_in[9];
    const float* bc   = (const float*)d_in[10];
    float* out = (float*)d_out;

    const int N = in_sizes[0] / HID;       // 50000
    const int E = in_sizes[1] / 2;         // 800000
    const int* src = ei;
    const int* dst = ei + E;

    char* p = (char*)d_ws;
    auto alloc = [&](size_t bytes) { void* r = (void*)p; p += (bytes + 255) & ~(size_t)255; return r; };
    int*   counts = (int*)alloc((size_t)N * 4);
    int*   rank   = (int*)alloc((size_t)E * 4);
    int*   rowptr = (int*)alloc((size_t)(N + 1) * 4);
    unsigned int* epk = (unsigned int*)alloc((size_t)E * 4);
    float* pooled = (float*)alloc((size_t)NGRAPH * NCLS * 4);
    unsigned short* Tb16 = (unsigned short*)alloc((size_t)N * HID * 2);
    unsigned short* Hb16 = (unsigned short*)alloc((size_t)N * HID * 2);
    float* T16    = (float*)alloc((size_t)N * NCLS * 4);
    unsigned short* Wt   = (unsigned short*)alloc((size_t)2 * HID * HID * 2);
    unsigned short* Wt2c = (unsigned short*)alloc((size_t)NCLS * 128 * 2);
    float* bc2    = (float*)alloc(NCLS * 4);

    k_init<<<(N + 255) / 256, 256, 0, stream>>>(counts, pooled, W0, W1, W2, Wc, b2, bc,
                                                Wt, Wt2c, bc2, N);
    k_hist<<<(E + 255) / 256, 256, 0, stream>>>(dst, counts, rank, E);
    k_scan<<<1, 1024, 0, stream>>>(counts, rowptr, N, E);
    k_fill<<<(E + 255) / 256, 256, 0, stream>>>(src, dst, rank, counts, rowptr, epk, E);

    const int gemm_grid = (N + 63) / 64;
    const int agg_grid  = ((size_t)N * 64 + 255) / 256;

    // layer 0
    k_gemm_f32<<<gemm_grid, 256, 0, stream>>>(x, Wt, Tb16, N);
    k_agg<<<agg_grid, 256, 0, stream>>>((const unsigned int*)Tb16, (unsigned int*)Hb16,
                                        rowptr, epk, b0, N);
    // layer 1 (+ folded layer-2 GEMM)
    k_gemm_bf16<<<gemm_grid, 256, 0, stream>>>(Hb16, Wt + 16384, Tb16, N);
    k_agg_fused<<<agg_grid, 256, 0, stream>>>((const unsigned int*)Tb16, T16,
                                              rowptr, epk, b1, Wt2c, N);
    // layer-2 aggregation fused with pooling
    k_agg16pool<<<agg_grid, 256, 0, stream>>>(T16, pooled, rowptr, epk, batch, N);
    // head
    k_head16<<<(NGRAPH * NCLS + 255) / 256, 256, 0, stream>>>(pooled, batch, bc2, out, N);
}

// Round 10
// 264.572 us; speedup vs baseline: 1.3587x; 1.3587x over previous
//
#include <hip/hip_runtime.h>
#include <hip/hip_bf16.h>
#include <hip/hip_fp16.h>

#define HID 128
#define NCLS 16
#define NGRAPH 64
#define CHUNK 1024

using bf16x8 = __attribute__((ext_vector_type(8))) short;
using f32x4  = __attribute__((ext_vector_type(4))) float;

// round-to-nearest-even f32 -> bf16
__device__ __forceinline__ unsigned int f2bf(float f) {
    unsigned int u = __float_as_uint(f);
    return (u + 0x7FFFu + ((u >> 16) & 1u)) >> 16;
}
__device__ __forceinline__ float bf2f_lo(unsigned int u) { return __uint_as_float(u << 16); }
__device__ __forceinline__ float bf2f_hi(unsigned int u) { return __uint_as_float(u & 0xFFFF0000u); }

// ---------------- init: zero counts/pooled + W0/W1 transpose-bf16 + W2@Wc fold ----------------
__global__ __launch_bounds__(256) void k_init(int* counts, float* pooled,
                                              const float* __restrict__ W0,
                                              const float* __restrict__ W1,
                                              const float* __restrict__ W2,
                                              const float* __restrict__ Wc,
                                              const float* __restrict__ b2,
                                              const float* __restrict__ bcin,
                                              unsigned short* __restrict__ Wt,
                                              unsigned short* __restrict__ Wt2c,
                                              float* __restrict__ bc2, int n) {
    int i = blockIdx.x * 256 + threadIdx.x;
    if (i < n) counts[i] = 0;
    if (i < NGRAPH * NCLS) pooled[i] = 0.0f;
    if (i < 2 * HID * HID) {           // Wt[m][col*128+k] = bf16(W[m][k*128+col])
        int m = i >> 14;
        int r = i & 16383;
        int c = r >> 7, k = r & 127;
        const float* W = (m == 0) ? W0 : W1;
        Wt[i] = (unsigned short)f2bf(W[k * HID + c]);
    }
    if (i < HID * NCLS) {              // Wt2c[c*128+k] = bf16(sum_j W2[k,j]*Wc[j,c])
        int k = i >> 4, c = i & 15;
        float s = 0.f;
        #pragma unroll 8
        for (int j = 0; j < HID; ++j)
            s = fmaf(W2[k * HID + j], Wc[j * NCLS + c], s);
        Wt2c[c * 128 + k] = (unsigned short)f2bf(s);
    }
    if (i < NCLS) {                    // bc2 = b2@Wc + bc
        float s = 0.f;
        for (int j = 0; j < HID; ++j)
            s = fmaf(b2[j], Wc[j * NCLS + i], s);
        bc2[i] = s + bcin[i];
    }
}

// ---------------- degree histogram over dst + per-edge rank ----------------
__global__ __launch_bounds__(256) void k_hist(const int* __restrict__ dst,
                                              int* counts, int* rank, int e) {
    int i = blockIdx.x * 256 + threadIdx.x;
    if (i < e) rank[i] = atomicAdd(&counts[dst[i]], 1);
}

// ---------------- scan step 1: per-chunk sums (coalesced, parallel blocks) ----------------
__global__ __launch_bounds__(256) void k_chunksum(const int* __restrict__ counts,
                                                  int* csum, int n) {
    __shared__ int sdata[256];
    int b = blockIdx.x, t = threadIdx.x;
    int base = b * CHUNK + t * 4;
    int s = 0;
    #pragma unroll
    for (int j = 0; j < 4; ++j) { int i = base + j; if (i < n) s += counts[i]; }
    sdata[t] = s; __syncthreads();
    for (int off = 128; off > 0; off >>= 1) {
        if (t < off) sdata[t] += sdata[t + off];
        __syncthreads();
    }
    if (t == 0) csum[b] = sdata[0];
}

// ---------------- rowptr: per-chunk exclusive scan (chunk offset in-block via wave reduce) ----------------
__global__ __launch_bounds__(256) void k_rowptr(const int* __restrict__ counts,
                                                const int* __restrict__ csum,
                                                int* rowptr, int n, int e) {
    __shared__ int sincl[256];
    __shared__ int s_coff;
    int b = blockIdx.x, t = threadIdx.x;
    if (t < 64) {
        int v = (t < b) ? csum[t] : 0;
        #pragma unroll
        for (int off = 32; off > 0; off >>= 1) v += __shfl_xor(v, off);
        if (t == 0) s_coff = v;
    }
    int base = b * CHUNK + t * 4;
    int v[4]; int s = 0;
    #pragma unroll
    for (int j = 0; j < 4; ++j) { int i = base + j; v[j] = (i < n) ? counts[i] : 0; s += v[j]; }
    sincl[t] = s; __syncthreads();
    for (int off = 1; off < 256; off <<= 1) {
        int x = sincl[t];
        int y = (t >= off) ? sincl[t - off] : 0;
        __syncthreads();
        sincl[t] = x + y;
        __syncthreads();
    }
    int run = s_coff + sincl[t] - s;
    #pragma unroll
    for (int j = 0; j < 4; ++j) {
        int i = base + j;
        if (i < n) { rowptr[i] = run; run += v[j]; }
    }
    if (b == 0 && t == 0) rowptr[n] = e;
}

// ---------------- CSR fill: 4B records {u16 src | fp16 norm}, no atomics ----------------
__global__ __launch_bounds__(256) void k_fill(const int* __restrict__ src,
                                              const int* __restrict__ dst,
                                              const int* __restrict__ rank,
                                              const int* __restrict__ counts,
                                              const int* __restrict__ rowptr,
                                              unsigned int* __restrict__ epk, int e) {
    int i = blockIdx.x * 256 + threadIdx.x;
    if (i >= e) return;
    int s = src[i], d = dst[i];
    int pos = rowptr[d] + rank[i];
    float norm = rsqrtf((float)(counts[s] + 1)) * rsqrtf((float)(counts[d] + 1));
    __half h = __float2half(norm);
    unsigned int hu = (unsigned int)__half_as_ushort(h);
    epk[pos] = (unsigned int)s | (hu << 16);
}

// ---------------- MFMA GEMM (f32 input, layer 0) ----------------
__global__ __launch_bounds__(256) void k_gemm_f32(const float* __restrict__ H,
                                                  const unsigned short* __restrict__ Wt,
                                                  unsigned short* __restrict__ Tb16, int n) {
    __shared__ char ldsA[64 * 256];
    int t = threadIdx.x;
    int cg = t & 31;
    int rg = t >> 5;
    int row0 = blockIdx.x * 64;

    #pragma unroll
    for (int i = 0; i < 8; ++i) {
        int lr = rg + i * 8;
        int r = row0 + lr;
        float4 v = make_float4(0.f, 0.f, 0.f, 0.f);
        if (r < n) v = ((const float4*)H)[(size_t)r * 32 + cg];
        uint2 pk;
        pk.x = f2bf(v.x) | (f2bf(v.y) << 16);
        pk.y = f2bf(v.z) | (f2bf(v.w) << 16);
        int byte = lr * 256 + cg * 8;
        *(uint2*)(ldsA + (byte ^ ((lr & 7) << 4))) = pk;
    }
    __syncthreads();

    int lane = t & 63;
    int w = t >> 6;
    int rsub = lane & 15;
    int kg = lane >> 4;
    int rowIdx = w * 16 + rsub;
    int abase = rowIdx * 256 + kg * 16;
    int aswz = (rowIdx & 7) << 4;

    f32x4 acc[8];
    #pragma unroll
    for (int nt = 0; nt < 8; ++nt) acc[nt] = (f32x4)(0.f);

    #pragma unroll
    for (int kk = 0; kk < 4; ++kk) {
        bf16x8 a = *(const bf16x8*)(ldsA + ((abase + kk * 64) ^ aswz));
        int k0 = kk * 32 + kg * 8;
        #pragma unroll
        for (int nt = 0; nt < 8; ++nt) {
            int col = nt * 16 + rsub;
            bf16x8 b = *(const bf16x8*)(Wt + col * 128 + k0);
            acc[nt] = __builtin_amdgcn_mfma_f32_16x16x32_bf16(a, b, acc[nt], 0, 0, 0);
        }
    }

    // C/D layout: col = lane&15, row = (lane>>4)*4 + reg
    #pragma unroll
    for (int nt = 0; nt < 8; ++nt) {
        #pragma unroll
        for (int j = 0; j < 4; ++j) {
            int row = row0 + w * 16 + kg * 4 + j;
            int col = nt * 16 + rsub;
            if (row < n) Tb16[(size_t)row * 128 + col] = (unsigned short)f2bf(acc[nt][j]);
        }
    }
}

// ---------------- MFMA GEMM (bf16 input, layer 1) ----------------
__global__ __launch_bounds__(256) void k_gemm_bf16(const unsigned short* __restrict__ Hb,
                                                   const unsigned short* __restrict__ Wt,
                                                   unsigned short* __restrict__ Tb16, int n) {
    __shared__ char ldsA[64 * 256];
    int t = threadIdx.x;
    int row0 = blockIdx.x * 64;
    int c16 = t & 15;
    int rbase = t >> 4;

    #pragma unroll
    for (int i = 0; i < 4; ++i) {
        int lr = rbase + i * 16;
        int r = row0 + lr;
        uint4 v = make_uint4(0u, 0u, 0u, 0u);
        if (r < n) v = *(const uint4*)(Hb + (size_t)r * 128 + c16 * 8);
        int byte = lr * 256 + c16 * 16;
        *(uint4*)(ldsA + (byte ^ ((lr & 7) << 4))) = v;
    }
    __syncthreads();

    int lane = t & 63;
    int w = t >> 6;
    int rsub = lane & 15;
    int kg = lane >> 4;
    int rowIdx = w * 16 + rsub;
    int abase = rowIdx * 256 + kg * 16;
    int aswz = (rowIdx & 7) << 4;

    f32x4 acc[8];
    #pragma unroll
    for (int nt = 0; nt < 8; ++nt) acc[nt] = (f32x4)(0.f);

    #pragma unroll
    for (int kk = 0; kk < 4; ++kk) {
        bf16x8 a = *(const bf16x8*)(ldsA + ((abase + kk * 64) ^ aswz));
        int k0 = kk * 32 + kg * 8;
        #pragma unroll
        for (int nt = 0; nt < 8; ++nt) {
            int col = nt * 16 + rsub;
            bf16x8 b = *(const bf16x8*)(Wt + col * 128 + k0);
            acc[nt] = __builtin_amdgcn_mfma_f32_16x16x32_bf16(a, b, acc[nt], 0, 0, 0);
        }
    }

    #pragma unroll
    for (int nt = 0; nt < 8; ++nt) {
        #pragma unroll
        for (int j = 0; j < 4; ++j) {
            int row = row0 + w * 16 + kg * 4 + j;
            int col = nt * 16 + rsub;
            if (row < n) Tb16[(size_t)row * 128 + col] = (unsigned short)f2bf(acc[nt][j]);
        }
    }
}

// ---------------- agg layer 0: bf16 gather, f32 acc -> relu bf16 out ----------------
__global__ __launch_bounds__(256) void k_agg(const unsigned int* __restrict__ Tb,
                                             unsigned int* __restrict__ outB,
                                             const int* __restrict__ rowptr,
                                             const unsigned int* __restrict__ epk,
                                             const float* __restrict__ bias, int n) {
    int wid = (blockIdx.x * 256 + threadIdx.x) >> 6;
    int lane = threadIdx.x & 63;
    if (wid >= n) return;
    float2 b2 = ((const float2*)bias)[lane];
    unsigned int us = Tb[(size_t)wid * 64 + lane];
    int start = rowptr[wid];
    int deg = rowptr[wid + 1] - start;
    float sn = 1.0f / (float)(deg + 1);
    float2 acc;
    acc.x = fmaf(bf2f_lo(us), sn, b2.x);
    acc.y = fmaf(bf2f_hi(us), sn, b2.y);

    for (int j0 = 0; j0 < deg; j0 += 64) {
        int myj = j0 + lane;
        unsigned int rec = 0;
        if (myj < deg) rec = epk[start + myj];
        int m = min(64, deg - j0);
        int jj = 0;
        for (; jj + 16 <= m; jj += 16) {
            unsigned int rr[16], uu[16];
            #pragma unroll
            for (int k = 0; k < 16; ++k) rr[k] = (unsigned int)__shfl((int)rec, jj + k);
            #pragma unroll
            for (int k = 0; k < 16; ++k) uu[k] = Tb[(size_t)(rr[k] & 0xFFFFu) * 64 + lane];
            #pragma unroll
            for (int k = 0; k < 16; ++k) {
                float wk = __half2float(__ushort_as_half((unsigned short)(rr[k] >> 16)));
                acc.x = fmaf(wk, bf2f_lo(uu[k]), acc.x);
                acc.y = fmaf(wk, bf2f_hi(uu[k]), acc.y);
            }
        }
        for (; jj + 4 <= m; jj += 4) {
            unsigned int rr[4], uu[4];
            #pragma unroll
            for (int k = 0; k < 4; ++k) rr[k] = (unsigned int)__shfl((int)rec, jj + k);
            #pragma unroll
            for (int k = 0; k < 4; ++k) uu[k] = Tb[(size_t)(rr[k] & 0xFFFFu) * 64 + lane];
            #pragma unroll
            for (int k = 0; k < 4; ++k) {
                float wk = __half2float(__ushort_as_half((unsigned short)(rr[k] >> 16)));
                acc.x = fmaf(wk, bf2f_lo(uu[k]), acc.x);
                acc.y = fmaf(wk, bf2f_hi(uu[k]), acc.y);
            }
        }
        for (; jj < m; ++jj) {
            unsigned int rj = (unsigned int)__shfl((int)rec, jj);
            unsigned int u = Tb[(size_t)(rj & 0xFFFFu) * 64 + lane];
            float wj = __half2float(__ushort_as_half((unsigned short)(rj >> 16)));
            acc.x = fmaf(wj, bf2f_lo(u), acc.x);
            acc.y = fmaf(wj, bf2f_hi(u), acc.y);
        }
    }

    float rx = fmaxf(acc.x, 0.f), ry = fmaxf(acc.y, 0.f);
    outB[(size_t)wid * 64 + lane] = f2bf(rx) | (f2bf(ry) << 16);
}

// ---------------- agg layer 1 FUSED with 16-wide GEMM (W2@Wc): T16[wid] = relu_bf16(agg) . W2c ----------------
__global__ __launch_bounds__(256) void k_agg_fused(const unsigned int* __restrict__ Tb,
                                                   float* __restrict__ T16,
                                                   const int* __restrict__ rowptr,
                                                   const unsigned int* __restrict__ epk,
                                                   const float* __restrict__ bias,
                                                   const unsigned short* __restrict__ Wt2c,
                                                   int n) {
    __shared__ unsigned int sh[4][64];
    int t = threadIdx.x;
    int wid = (blockIdx.x * 256 + t) >> 6;
    int lane = t & 63;
    int w = t >> 6;
    int c = lane & 15;            // output class
    int half = lane >> 4;         // k-quarter 0..3
    bool valid = wid < n;

    float2 acc = make_float2(0.f, 0.f);
    int start = 0, deg = 0;
    if (valid) {
        float2 b2 = ((const float2*)bias)[lane];
        unsigned int us = Tb[(size_t)wid * 64 + lane];
        start = rowptr[wid];
        deg = rowptr[wid + 1] - start;
        float sn = 1.0f / (float)(deg + 1);
        acc.x = fmaf(bf2f_lo(us), sn, b2.x);
        acc.y = fmaf(bf2f_hi(us), sn, b2.y);
    }

    for (int j0 = 0; j0 < deg; j0 += 64) {
        int myj = j0 + lane;
        unsigned int rec = 0;
        if (myj < deg) rec = epk[start + myj];
        int m = min(64, deg - j0);
        int jj = 0;
        for (; jj + 16 <= m; jj += 16) {
            unsigned int rr[16], uu[16];
            #pragma unroll
            for (int k = 0; k < 16; ++k) rr[k] = (unsigned int)__shfl((int)rec, jj + k);
            #pragma unroll
            for (int k = 0; k < 16; ++k) uu[k] = Tb[(size_t)(rr[k] & 0xFFFFu) * 64 + lane];
            #pragma unroll
            for (int k = 0; k < 16; ++k) {
                float wk = __half2float(__ushort_as_half((unsigned short)(rr[k] >> 16)));
                acc.x = fmaf(wk, bf2f_lo(uu[k]), acc.x);
                acc.y = fmaf(wk, bf2f_hi(uu[k]), acc.y);
            }
        }
        for (; jj + 4 <= m; jj += 4) {
            unsigned int rr[4], uu[4];
            #pragma unroll
            for (int k = 0; k < 4; ++k) rr[k] = (unsigned int)__shfl((int)rec, jj + k);
            #pragma unroll
            for (int k = 0; k < 4; ++k) uu[k] = Tb[(size_t)(rr[k] & 0xFFFFu) * 64 + lane];
            #pragma unroll
            for (int k = 0; k < 4; ++k) {
                float wk = __half2float(__ushort_as_half((unsigned short)(rr[k] >> 16)));
                acc.x = fmaf(wk, bf2f_lo(uu[k]), acc.x);
                acc.y = fmaf(wk, bf2f_hi(uu[k]), acc.y);
            }
        }
        for (; jj < m; ++jj) {
            unsigned int rj = (unsigned int)__shfl((int)rec, jj);
            unsigned int u = Tb[(size_t)(rj & 0xFFFFu) * 64 + lane];
            float wj = __half2float(__ushort_as_half((unsigned short)(rj >> 16)));
            acc.x = fmaf(wj, bf2f_lo(u), acc.x);
            acc.y = fmaf(wj, bf2f_hi(u), acc.y);
        }
    }

    // relu + bf16-round, stage per-wave in LDS
    float rx = fmaxf(acc.x, 0.f), ry = fmaxf(acc.y, 0.f);
    sh[w][lane] = f2bf(rx) | (f2bf(ry) << 16);
    __syncthreads();

    // load W2c slice AFTER the gather loop (keeps gather-loop VGPR low)
    const uint4* wq = (const uint4*)((const unsigned int*)Wt2c + (c * 64 + half * 16));
    uint4 wv0 = wq[0], wv1 = wq[1], wv2 = wq[2], wv3 = wq[3];

    float part = 0.f;
    #pragma unroll
    for (int kk = 0; kk < 4; ++kk) {
        unsigned int hu = sh[w][half * 16 + kk];
        unsigned int wu = (&wv0.x)[kk];
        part = fmaf(bf2f_lo(hu), bf2f_lo(wu), part);
        part = fmaf(bf2f_hi(hu), bf2f_hi(wu), part);
    }
    #pragma unroll
    for (int kk = 0; kk < 4; ++kk) {
        unsigned int hu = sh[w][half * 16 + 4 + kk];
        unsigned int wu = (&wv1.x)[kk];
        part = fmaf(bf2f_lo(hu), bf2f_lo(wu), part);
        part = fmaf(bf2f_hi(hu), bf2f_hi(wu), part);
    }
    #pragma unroll
    for (int kk = 0; kk < 4; ++kk) {
        unsigned int hu = sh[w][half * 16 + 8 + kk];
        unsigned int wu = (&wv2.x)[kk];
        part = fmaf(bf2f_lo(hu), bf2f_lo(wu), part);
        part = fmaf(bf2f_hi(hu), bf2f_hi(wu), part);
    }
    #pragma unroll
    for (int kk = 0; kk < 4; ++kk) {
        unsigned int hu = sh[w][half * 16 + 12 + kk];
        unsigned int wu = (&wv3.x)[kk];
        part = fmaf(bf2f_lo(hu), bf2f_lo(wu), part);
        part = fmaf(bf2f_hi(hu), bf2f_hi(wu), part);
    }
    part += __shfl_xor(part, 16);
    part += __shfl_xor(part, 32);

    if (valid && half == 0) T16[(size_t)wid * 16 + c] = part;
}

// ---------------- agg16 + pool FUSED: gather T16 (L2-resident), atomicAdd into pooled ----------------
__global__ __launch_bounds__(256) void k_agg16pool(const float* __restrict__ T16,
                                                   float* __restrict__ pooled,
                                                   const int* __restrict__ rowptr,
                                                   const unsigned int* __restrict__ epk,
                                                   const int* __restrict__ batch, int n) {
    int wid = (blockIdx.x * 256 + threadIdx.x) >> 6;
    int lane = threadIdx.x & 63;
    if (wid >= n) return;
    int p = lane & 15;
    int q = lane >> 4;
    int start = rowptr[wid];
    int deg = rowptr[wid + 1] - start;

    float acc = 0.f;
    if (q == 0) {
        float sn = 1.0f / (float)(deg + 1);
        acc = T16[(size_t)wid * 16 + p] * sn;
    }

    for (int j0 = 0; j0 < deg; j0 += 64) {
        int myj = j0 + lane;
        unsigned int rec = 0;
        if (myj < deg) rec = epk[start + myj];
        int m = min(64, deg - j0);
        int mg = (m - q + 3) >> 2;
        int jj = 0;
        for (; jj + 8 <= mg; jj += 8) {
            unsigned int rr[8]; float uu[8];
            #pragma unroll
            for (int k = 0; k < 8; ++k) rr[k] = (unsigned int)__shfl((int)rec, 4 * (jj + k) + q);
            #pragma unroll
            for (int k = 0; k < 8; ++k) uu[k] = T16[(size_t)(rr[k] & 0xFFFFu) * 16 + p];
            #pragma unroll
            for (int k = 0; k < 8; ++k) {
                float wk = __half2float(__ushort_as_half((unsigned short)(rr[k] >> 16)));
                acc = fmaf(wk, uu[k], acc);
            }
        }
        for (; jj < mg; ++jj) {
            unsigned int rj = (unsigned int)__shfl((int)rec, 4 * jj + q);
            float u = T16[(size_t)(rj & 0xFFFFu) * 16 + p];
            float wj = __half2float(__ushort_as_half((unsigned short)(rj >> 16)));
            acc = fmaf(wj, u, acc);
        }
    }

    acc += __shfl_xor(acc, 16);
    acc += __shfl_xor(acc, 32);

    if (q == 0) atomicAdd(&pooled[batch[wid] * NCLS + p], acc);
}

// ---------------- head: out[g,c] = pooled[g,c]/cnt(g) + bc2[c]; cnt via bsearch on sorted batch ----------------
__global__ __launch_bounds__(256) void k_head16(const float* __restrict__ pooled,
                                                const int* __restrict__ batch,
                                                const float* __restrict__ bc2,
                                                float* __restrict__ out, int n) {
    int idx = blockIdx.x * 256 + threadIdx.x;
    if (idx >= NGRAPH * NCLS) return;
    int g = idx >> 4, c = idx & 15;
    int lo = 0, hi = n;
    while (lo < hi) { int mid = (lo + hi) >> 1; if (batch[mid] < g) lo = mid + 1; else hi = mid; }
    int lb = lo;
    lo = 0; hi = n;
    while (lo < hi) { int mid = (lo + hi) >> 1; if (batch[mid] < g + 1) lo = mid + 1; else hi = mid; }
    float cnt = (float)(lo - lb);
    float inv = 1.0f / fmaxf(cnt, 1.0f);
    out[idx] = pooled[idx] * inv + bc2[c];
}

extern "C" void kernel_launch(void* const* d_in, const int* in_sizes, int n_in,
                              void* d_out, int out_size, void* d_ws, size_t ws_size,
                              hipStream_t stream) {
    const float* x    = (const float*)d_in[0];
    const int*   ei   = (const int*)d_in[1];
    const int*   batch= (const int*)d_in[2];
    const float* W0   = (const float*)d_in[3];
    const float* b0   = (const float*)d_in[4];
    const float* W1   = (const float*)d_in[5];
    const float* b1   = (const float*)d_in[6];
    const float* W2   = (const float*)d_in[7];
    const float* b2   = (const float*)d_in[8];
    const float* Wc   = (const float*)d_in[9];
    const float* bc   = (const float*)d_in[10];
    float* out = (float*)d_out;

    const int N = in_sizes[0] / HID;       // 50000
    const int E = in_sizes[1] / 2;         // 800000
    const int* src = ei;
    const int* dst = ei + E;

    char* p = (char*)d_ws;
    auto alloc = [&](size_t bytes) { void* r = (void*)p; p += (bytes + 255) & ~(size_t)255; return r; };
    int*   counts = (int*)alloc((size_t)N * 4);
    int*   rank   = (int*)alloc((size_t)E * 4);
    int*   csum   = (int*)alloc(256 * 4);
    int*   rowptr = (int*)alloc((size_t)(N + 1) * 4);
    unsigned int* epk = (unsigned int*)alloc((size_t)E * 4);
    float* pooled = (float*)alloc((size_t)NGRAPH * NCLS * 4);
    unsigned short* Tb16 = (unsigned short*)alloc((size_t)N * HID * 2);
    unsigned short* Hb16 = (unsigned short*)alloc((size_t)N * HID * 2);
    float* T16    = (float*)alloc((size_t)N * NCLS * 4);
    unsigned short* Wt   = (unsigned short*)alloc((size_t)2 * HID * HID * 2);
    unsigned short* Wt2c = (unsigned short*)alloc((size_t)NCLS * 128 * 2);
    float* bc2    = (float*)alloc(NCLS * 4);

    const int NB = (N + CHUNK - 1) / CHUNK;

    k_init<<<(N + 255) / 256, 256, 0, stream>>>(counts, pooled, W0, W1, W2, Wc, b2, bc,
                                                Wt, Wt2c, bc2, N);
    k_hist<<<(E + 255) / 256, 256, 0, stream>>>(dst, counts, rank, E);
    k_chunksum<<<NB, 256, 0, stream>>>(counts, csum, N);
    k_rowptr<<<NB, 256, 0, stream>>>(counts, csum, rowptr, N, E);
    k_fill<<<(E + 255) / 256, 256, 0, stream>>>(src, dst, rank, counts, rowptr, epk, E);

    const int gemm_grid = (N + 63) / 64;
    const int agg_grid  = ((size_t)N * 64 + 255) / 256;

    // layer 0
    k_gemm_f32<<<gemm_grid, 256, 0, stream>>>(x, Wt, Tb16, N);
    k_agg<<<agg_grid, 256, 0, stream>>>((const unsigned int*)Tb16, (unsigned int*)Hb16,
                                        rowptr, epk, b0, N);
    // layer 1 (+ folded layer-2 GEMM)
    k_gemm_bf16<<<gemm_grid, 256, 0, stream>>>(Hb16, Wt + 16384, Tb16, N);
    k_agg_fused<<<agg_grid, 256, 0, stream>>>((const unsigned int*)Tb16, T16,
                                              rowptr, epk, b1, Wt2c, N);
    // layer-2 aggregation fused with pooling
    k_agg16pool<<<agg_grid, 256, 0, stream>>>(T16, pooled, rowptr, epk, batch, N);
    // head
    k_head16<<<(NGRAPH * NCLS + 255) / 256, 256, 0, stream>>>(pooled, batch, bc2, out, N);
}

// Round 11
// 235.485 us; speedup vs baseline: 1.5266x; 1.1235x over previous
//
#include <hip/hip_runtime.h>
#include <hip/hip_bf16.h>
#include <hip/hip_fp16.h>

#define HID 128
#define NCLS 16
#define NGRAPH 64
#define CHUNK 1024

using bf16x8 = __attribute__((ext_vector_type(8))) short;
using f32x4  = __attribute__((ext_vector_type(4))) float;

// round-to-nearest-even f32 -> bf16
__device__ __forceinline__ unsigned int f2bf(float f) {
    unsigned int u = __float_as_uint(f);
    return (u + 0x7FFFu + ((u >> 16) & 1u)) >> 16;
}
__device__ __forceinline__ float bf2f_lo(unsigned int u) { return __uint_as_float(u << 16); }
__device__ __forceinline__ float bf2f_hi(unsigned int u) { return __uint_as_float(u & 0xFFFF0000u); }

// ---------------- init: zero counts/pooled + W0/W1 transpose-bf16 + W2@Wc fold ----------------
__global__ __launch_bounds__(256) void k_init(int* counts, float* pooled,
                                              const float* __restrict__ W0,
                                              const float* __restrict__ W1,
                                              const float* __restrict__ W2,
                                              const float* __restrict__ Wc,
                                              const float* __restrict__ b2,
                                              const float* __restrict__ bcin,
                                              unsigned short* __restrict__ Wt,
                                              unsigned short* __restrict__ Wt2c,
                                              float* __restrict__ bc2, int n) {
    int i = blockIdx.x * 256 + threadIdx.x;
    if (i < n) counts[i] = 0;
    if (i < NGRAPH * NCLS) pooled[i] = 0.0f;
    if (i < 2 * HID * HID) {           // Wt[m][col*128+k] = bf16(W[m][k*128+col])
        int m = i >> 14;
        int r = i & 16383;
        int c = r >> 7, k = r & 127;
        const float* W = (m == 0) ? W0 : W1;
        Wt[i] = (unsigned short)f2bf(W[k * HID + c]);
    }
    if (i < HID * NCLS) {              // Wt2c[c*128+k] = bf16(sum_j W2[k,j]*Wc[j,c])
        int k = i >> 4, c = i & 15;
        float s = 0.f;
        #pragma unroll 8
        for (int j = 0; j < HID; ++j)
            s = fmaf(W2[k * HID + j], Wc[j * NCLS + c], s);
        Wt2c[c * 128 + k] = (unsigned short)f2bf(s);
    }
    if (i < NCLS) {                    // bc2 = b2@Wc + bc
        float s = 0.f;
        for (int j = 0; j < HID; ++j)
            s = fmaf(b2[j], Wc[j * NCLS + i], s);
        bc2[i] = s + bcin[i];
    }
}

// ---------------- degree histogram over dst + per-edge rank ----------------
__global__ __launch_bounds__(256) void k_hist(const int* __restrict__ dst,
                                              int* counts, int* rank, int e) {
    int i = blockIdx.x * 256 + threadIdx.x;
    if (i < e) rank[i] = atomicAdd(&counts[dst[i]], 1);
}

// ---------------- scan step 1: per-chunk sums (coalesced, parallel blocks) ----------------
__global__ __launch_bounds__(256) void k_chunksum(const int* __restrict__ counts,
                                                  int* csum, int n) {
    __shared__ int sdata[256];
    int b = blockIdx.x, t = threadIdx.x;
    int base = b * CHUNK + t * 4;
    int s = 0;
    #pragma unroll
    for (int j = 0; j < 4; ++j) { int i = base + j; if (i < n) s += counts[i]; }
    sdata[t] = s; __syncthreads();
    for (int off = 128; off > 0; off >>= 1) {
        if (t < off) sdata[t] += sdata[t + off];
        __syncthreads();
    }
    if (t == 0) csum[b] = sdata[0];
}

// ---------------- rowptr: per-chunk exclusive scan (chunk offset in-block via wave reduce) ----------------
__global__ __launch_bounds__(256) void k_rowptr(const int* __restrict__ counts,
                                                const int* __restrict__ csum,
                                                int* rowptr, int n, int e) {
    __shared__ int sincl[256];
    __shared__ int s_coff;
    int b = blockIdx.x, t = threadIdx.x;
    if (t < 64) {
        int v = (t < b) ? csum[t] : 0;
        #pragma unroll
        for (int off = 32; off > 0; off >>= 1) v += __shfl_xor(v, off);
        if (t == 0) s_coff = v;
    }
    int base = b * CHUNK + t * 4;
    int v[4]; int s = 0;
    #pragma unroll
    for (int j = 0; j < 4; ++j) { int i = base + j; v[j] = (i < n) ? counts[i] : 0; s += v[j]; }
    sincl[t] = s; __syncthreads();
    for (int off = 1; off < 256; off <<= 1) {
        int x = sincl[t];
        int y = (t >= off) ? sincl[t - off] : 0;
        __syncthreads();
        sincl[t] = x + y;
        __syncthreads();
    }
    int run = s_coff + sincl[t] - s;
    #pragma unroll
    for (int j = 0; j < 4; ++j) {
        int i = base + j;
        if (i < n) { rowptr[i] = run; run += v[j]; }
    }
    if (b == 0 && t == 0) rowptr[n] = e;
}

// ---------------- CSR fill: 4B records {u16 src | fp16 norm}, no atomics ----------------
__global__ __launch_bounds__(256) void k_fill(const int* __restrict__ src,
                                              const int* __restrict__ dst,
                                              const int* __restrict__ rank,
                                              const int* __restrict__ counts,
                                              const int* __restrict__ rowptr,
                                              unsigned int* __restrict__ epk, int e) {
    int i = blockIdx.x * 256 + threadIdx.x;
    if (i >= e) return;
    int s = src[i], d = dst[i];
    int pos = rowptr[d] + rank[i];
    float norm = rsqrtf((float)(counts[s] + 1)) * rsqrtf((float)(counts[d] + 1));
    __half h = __float2half(norm);
    unsigned int hu = (unsigned int)__half_as_ushort(h);
    epk[pos] = (unsigned int)s | (hu << 16);
}

// ---------------- MFMA GEMM (f32 input, layer 0) ----------------
__global__ __launch_bounds__(256) void k_gemm_f32(const float* __restrict__ H,
                                                  const unsigned short* __restrict__ Wt,
                                                  unsigned short* __restrict__ Tb16, int n) {
    __shared__ char ldsA[64 * 256];
    int t = threadIdx.x;
    int cg = t & 31;
    int rg = t >> 5;
    int row0 = blockIdx.x * 64;

    #pragma unroll
    for (int i = 0; i < 8; ++i) {
        int lr = rg + i * 8;
        int r = row0 + lr;
        float4 v = make_float4(0.f, 0.f, 0.f, 0.f);
        if (r < n) v = ((const float4*)H)[(size_t)r * 32 + cg];
        uint2 pk;
        pk.x = f2bf(v.x) | (f2bf(v.y) << 16);
        pk.y = f2bf(v.z) | (f2bf(v.w) << 16);
        int byte = lr * 256 + cg * 8;
        *(uint2*)(ldsA + (byte ^ ((lr & 7) << 4))) = pk;
    }
    __syncthreads();

    int lane = t & 63;
    int w = t >> 6;
    int rsub = lane & 15;
    int kg = lane >> 4;
    int rowIdx = w * 16 + rsub;
    int abase = rowIdx * 256 + kg * 16;
    int aswz = (rowIdx & 7) << 4;

    f32x4 acc[8];
    #pragma unroll
    for (int nt = 0; nt < 8; ++nt) acc[nt] = (f32x4)(0.f);

    #pragma unroll
    for (int kk = 0; kk < 4; ++kk) {
        bf16x8 a = *(const bf16x8*)(ldsA + ((abase + kk * 64) ^ aswz));
        int k0 = kk * 32 + kg * 8;
        #pragma unroll
        for (int nt = 0; nt < 8; ++nt) {
            int col = nt * 16 + rsub;
            bf16x8 b = *(const bf16x8*)(Wt + col * 128 + k0);
            acc[nt] = __builtin_amdgcn_mfma_f32_16x16x32_bf16(a, b, acc[nt], 0, 0, 0);
        }
    }

    // C/D layout: col = lane&15, row = (lane>>4)*4 + reg
    #pragma unroll
    for (int nt = 0; nt < 8; ++nt) {
        #pragma unroll
        for (int j = 0; j < 4; ++j) {
            int row = row0 + w * 16 + kg * 4 + j;
            int col = nt * 16 + rsub;
            if (row < n) Tb16[(size_t)row * 128 + col] = (unsigned short)f2bf(acc[nt][j]);
        }
    }
}

// ---------------- MFMA GEMM (bf16 input, layer 1) ----------------
__global__ __launch_bounds__(256) void k_gemm_bf16(const unsigned short* __restrict__ Hb,
                                                   const unsigned short* __restrict__ Wt,
                                                   unsigned short* __restrict__ Tb16, int n) {
    __shared__ char ldsA[64 * 256];
    int t = threadIdx.x;
    int row0 = blockIdx.x * 64;
    int c16 = t & 15;
    int rbase = t >> 4;

    #pragma unroll
    for (int i = 0; i < 4; ++i) {
        int lr = rbase + i * 16;
        int r = row0 + lr;
        uint4 v = make_uint4(0u, 0u, 0u, 0u);
        if (r < n) v = *(const uint4*)(Hb + (size_t)r * 128 + c16 * 8);
        int byte = lr * 256 + c16 * 16;
        *(uint4*)(ldsA + (byte ^ ((lr & 7) << 4))) = v;
    }
    __syncthreads();

    int lane = t & 63;
    int w = t >> 6;
    int rsub = lane & 15;
    int kg = lane >> 4;
    int rowIdx = w * 16 + rsub;
    int abase = rowIdx * 256 + kg * 16;
    int aswz = (rowIdx & 7) << 4;

    f32x4 acc[8];
    #pragma unroll
    for (int nt = 0; nt < 8; ++nt) acc[nt] = (f32x4)(0.f);

    #pragma unroll
    for (int kk = 0; kk < 4; ++kk) {
        bf16x8 a = *(const bf16x8*)(ldsA + ((abase + kk * 64) ^ aswz));
        int k0 = kk * 32 + kg * 8;
        #pragma unroll
        for (int nt = 0; nt < 8; ++nt) {
            int col = nt * 16 + rsub;
            bf16x8 b = *(const bf16x8*)(Wt + col * 128 + k0);
            acc[nt] = __builtin_amdgcn_mfma_f32_16x16x32_bf16(a, b, acc[nt], 0, 0, 0);
        }
    }

    #pragma unroll
    for (int nt = 0; nt < 8; ++nt) {
        #pragma unroll
        for (int j = 0; j < 4; ++j) {
            int row = row0 + w * 16 + kg * 4 + j;
            int col = nt * 16 + rsub;
            if (row < n) Tb16[(size_t)row * 128 + col] = (unsigned short)f2bf(acc[nt][j]);
        }
    }
}

// ---------------- agg layer 0: bf16 gather, f32 acc -> relu bf16 out ----------------
__global__ __launch_bounds__(256) void k_agg(const unsigned int* __restrict__ Tb,
                                             unsigned int* __restrict__ outB,
                                             const int* __restrict__ rowptr,
                                             const unsigned int* __restrict__ epk,
                                             const float* __restrict__ bias, int n) {
    int wid = (blockIdx.x * 256 + threadIdx.x) >> 6;
    int lane = threadIdx.x & 63;
    if (wid >= n) return;
    float2 b2 = ((const float2*)bias)[lane];
    unsigned int us = Tb[(size_t)wid * 64 + lane];
    int start = rowptr[wid];
    int deg = rowptr[wid + 1] - start;
    float sn = 1.0f / (float)(deg + 1);
    float2 acc;
    acc.x = fmaf(bf2f_lo(us), sn, b2.x);
    acc.y = fmaf(bf2f_hi(us), sn, b2.y);

    for (int j0 = 0; j0 < deg; j0 += 64) {
        int myj = j0 + lane;
        unsigned int rec = 0;
        if (myj < deg) rec = epk[start + myj];
        int m = min(64, deg - j0);
        int jj = 0;
        for (; jj + 16 <= m; jj += 16) {
            unsigned int rr[16], uu[16];
            #pragma unroll
            for (int k = 0; k < 16; ++k) rr[k] = (unsigned int)__shfl((int)rec, jj + k);
            #pragma unroll
            for (int k = 0; k < 16; ++k) uu[k] = Tb[(size_t)(rr[k] & 0xFFFFu) * 64 + lane];
            #pragma unroll
            for (int k = 0; k < 16; ++k) {
                float wk = __half2float(__ushort_as_half((unsigned short)(rr[k] >> 16)));
                acc.x = fmaf(wk, bf2f_lo(uu[k]), acc.x);
                acc.y = fmaf(wk, bf2f_hi(uu[k]), acc.y);
            }
        }
        for (; jj + 4 <= m; jj += 4) {
            unsigned int rr[4], uu[4];
            #pragma unroll
            for (int k = 0; k < 4; ++k) rr[k] = (unsigned int)__shfl((int)rec, jj + k);
            #pragma unroll
            for (int k = 0; k < 4; ++k) uu[k] = Tb[(size_t)(rr[k] & 0xFFFFu) * 64 + lane];
            #pragma unroll
            for (int k = 0; k < 4; ++k) {
                float wk = __half2float(__ushort_as_half((unsigned short)(rr[k] >> 16)));
                acc.x = fmaf(wk, bf2f_lo(uu[k]), acc.x);
                acc.y = fmaf(wk, bf2f_hi(uu[k]), acc.y);
            }
        }
        for (; jj < m; ++jj) {
            unsigned int rj = (unsigned int)__shfl((int)rec, jj);
            unsigned int u = Tb[(size_t)(rj & 0xFFFFu) * 64 + lane];
            float wj = __half2float(__ushort_as_half((unsigned short)(rj >> 16)));
            acc.x = fmaf(wj, bf2f_lo(u), acc.x);
            acc.y = fmaf(wj, bf2f_hi(u), acc.y);
        }
    }

    float rx = fmaxf(acc.x, 0.f), ry = fmaxf(acc.y, 0.f);
    outB[(size_t)wid * 64 + lane] = f2bf(rx) | (f2bf(ry) << 16);
}

// ---------------- agg layer 1 FUSED with 16-wide GEMM (W2@Wc): T16[wid] = relu_bf16(agg) . W2c ----------------
__global__ __launch_bounds__(256) void k_agg_fused(const unsigned int* __restrict__ Tb,
                                                   float* __restrict__ T16,
                                                   const int* __restrict__ rowptr,
                                                   const unsigned int* __restrict__ epk,
                                                   const float* __restrict__ bias,
                                                   const unsigned short* __restrict__ Wt2c,
                                                   int n) {
    __shared__ unsigned int sh[4][64];
    int t = threadIdx.x;
    int wid = (blockIdx.x * 256 + t) >> 6;
    int lane = t & 63;
    int w = t >> 6;
    int c = lane & 15;            // output class
    int half = lane >> 4;         // k-quarter 0..3
    bool valid = wid < n;

    float2 acc = make_float2(0.f, 0.f);
    int start = 0, deg = 0;
    if (valid) {
        float2 b2 = ((const float2*)bias)[lane];
        unsigned int us = Tb[(size_t)wid * 64 + lane];
        start = rowptr[wid];
        deg = rowptr[wid + 1] - start;
        float sn = 1.0f / (float)(deg + 1);
        acc.x = fmaf(bf2f_lo(us), sn, b2.x);
        acc.y = fmaf(bf2f_hi(us), sn, b2.y);
    }

    for (int j0 = 0; j0 < deg; j0 += 64) {
        int myj = j0 + lane;
        unsigned int rec = 0;
        if (myj < deg) rec = epk[start + myj];
        int m = min(64, deg - j0);
        int jj = 0;
        for (; jj + 16 <= m; jj += 16) {
            unsigned int rr[16], uu[16];
            #pragma unroll
            for (int k = 0; k < 16; ++k) rr[k] = (unsigned int)__shfl((int)rec, jj + k);
            #pragma unroll
            for (int k = 0; k < 16; ++k) uu[k] = Tb[(size_t)(rr[k] & 0xFFFFu) * 64 + lane];
            #pragma unroll
            for (int k = 0; k < 16; ++k) {
                float wk = __half2float(__ushort_as_half((unsigned short)(rr[k] >> 16)));
                acc.x = fmaf(wk, bf2f_lo(uu[k]), acc.x);
                acc.y = fmaf(wk, bf2f_hi(uu[k]), acc.y);
            }
        }
        for (; jj + 4 <= m; jj += 4) {
            unsigned int rr[4], uu[4];
            #pragma unroll
            for (int k = 0; k < 4; ++k) rr[k] = (unsigned int)__shfl((int)rec, jj + k);
            #pragma unroll
            for (int k = 0; k < 4; ++k) uu[k] = Tb[(size_t)(rr[k] & 0xFFFFu) * 64 + lane];
            #pragma unroll
            for (int k = 0; k < 4; ++k) {
                float wk = __half2float(__ushort_as_half((unsigned short)(rr[k] >> 16)));
                acc.x = fmaf(wk, bf2f_lo(uu[k]), acc.x);
                acc.y = fmaf(wk, bf2f_hi(uu[k]), acc.y);
            }
        }
        for (; jj < m; ++jj) {
            unsigned int rj = (unsigned int)__shfl((int)rec, jj);
            unsigned int u = Tb[(size_t)(rj & 0xFFFFu) * 64 + lane];
            float wj = __half2float(__ushort_as_half((unsigned short)(rj >> 16)));
            acc.x = fmaf(wj, bf2f_lo(u), acc.x);
            acc.y = fmaf(wj, bf2f_hi(u), acc.y);
        }
    }

    // relu + bf16-round, stage per-wave in LDS
    float rx = fmaxf(acc.x, 0.f), ry = fmaxf(acc.y, 0.f);
    sh[w][lane] = f2bf(rx) | (f2bf(ry) << 16);
    __syncthreads();

    // load W2c slice AFTER the gather loop (keeps gather-loop VGPR low)
    const uint4* wq = (const uint4*)((const unsigned int*)Wt2c + (c * 64 + half * 16));
    uint4 wv0 = wq[0], wv1 = wq[1], wv2 = wq[2], wv3 = wq[3];

    float part = 0.f;
    #pragma unroll
    for (int kk = 0; kk < 4; ++kk) {
        unsigned int hu = sh[w][half * 16 + kk];
        unsigned int wu = (&wv0.x)[kk];
        part = fmaf(bf2f_lo(hu), bf2f_lo(wu), part);
        part = fmaf(bf2f_hi(hu), bf2f_hi(wu), part);
    }
    #pragma unroll
    for (int kk = 0; kk < 4; ++kk) {
        unsigned int hu = sh[w][half * 16 + 4 + kk];
        unsigned int wu = (&wv1.x)[kk];
        part = fmaf(bf2f_lo(hu), bf2f_lo(wu), part);
        part = fmaf(bf2f_hi(hu), bf2f_hi(wu), part);
    }
    #pragma unroll
    for (int kk = 0; kk < 4; ++kk) {
        unsigned int hu = sh[w][half * 16 + 8 + kk];
        unsigned int wu = (&wv2.x)[kk];
        part = fmaf(bf2f_lo(hu), bf2f_lo(wu), part);
        part = fmaf(bf2f_hi(hu), bf2f_hi(wu), part);
    }
    #pragma unroll
    for (int kk = 0; kk < 4; ++kk) {
        unsigned int hu = sh[w][half * 16 + 12 + kk];
        unsigned int wu = (&wv3.x)[kk];
        part = fmaf(bf2f_lo(hu), bf2f_lo(wu), part);
        part = fmaf(bf2f_hi(hu), bf2f_hi(wu), part);
    }
    part += __shfl_xor(part, 16);
    part += __shfl_xor(part, 32);

    if (valid && half == 0) T16[(size_t)wid * 16 + c] = part;
}

// ---------------- agg16: gather T16 (L2-resident 64B rows) -> G16, no atomics ----------------
__global__ __launch_bounds__(256) void k_agg16(const float* __restrict__ T16,
                                               float* __restrict__ G16,
                                               const int* __restrict__ rowptr,
                                               const unsigned int* __restrict__ epk, int n) {
    int wid = (blockIdx.x * 256 + threadIdx.x) >> 6;
    int lane = threadIdx.x & 63;
    if (wid >= n) return;
    int p = lane & 15;
    int q = lane >> 4;
    int start = rowptr[wid];
    int deg = rowptr[wid + 1] - start;

    float acc = 0.f;
    if (q == 0) {
        float sn = 1.0f / (float)(deg + 1);
        acc = T16[(size_t)wid * 16 + p] * sn;
    }

    for (int j0 = 0; j0 < deg; j0 += 64) {
        int myj = j0 + lane;
        unsigned int rec = 0;
        if (myj < deg) rec = epk[start + myj];
        int m = min(64, deg - j0);
        int mg = (m - q + 3) >> 2;
        int jj = 0;
        for (; jj + 8 <= mg; jj += 8) {
            unsigned int rr[8]; float uu[8];
            #pragma unroll
            for (int k = 0; k < 8; ++k) rr[k] = (unsigned int)__shfl((int)rec, 4 * (jj + k) + q);
            #pragma unroll
            for (int k = 0; k < 8; ++k) uu[k] = T16[(size_t)(rr[k] & 0xFFFFu) * 16 + p];
            #pragma unroll
            for (int k = 0; k < 8; ++k) {
                float wk = __half2float(__ushort_as_half((unsigned short)(rr[k] >> 16)));
                acc = fmaf(wk, uu[k], acc);
            }
        }
        for (; jj < mg; ++jj) {
            unsigned int rj = (unsigned int)__shfl((int)rec, 4 * jj + q);
            float u = T16[(size_t)(rj & 0xFFFFu) * 16 + p];
            float wj = __half2float(__ushort_as_half((unsigned short)(rj >> 16)));
            acc = fmaf(wj, u, acc);
        }
    }

    acc += __shfl_xor(acc, 16);
    acc += __shfl_xor(acc, 32);

    if (q == 0) G16[(size_t)wid * 16 + p] = acc;
}

// ---------------- pool16: run-length segment-sum over sorted batch (few atomics) ----------------
// one wave per 64-node chunk; p = lane&15 feature, q = lane>>4 node subgroup (stride 4)
__global__ __launch_bounds__(256) void k_pool16(const float* __restrict__ G16,
                                                const int* __restrict__ batch,
                                                float* pooled, int n) {
    int gw = (blockIdx.x * 256 + threadIdx.x) >> 6;
    int lane = threadIdx.x & 63;
    int p = lane & 15;
    int q = lane >> 4;
    int n0 = gw * 64;
    if (n0 >= n) return;
    int n1 = min(n0 + 64, n);
    int i0 = n0 + q;
    if (i0 >= n1) return;
    int gprev = batch[i0];
    float acc = 0.f;
    for (int i = i0; i < n1; i += 4) {
        int g = batch[i];
        if (g != gprev) {               // uniform within the 16-lane subgroup
            atomicAdd(&pooled[gprev * NCLS + p], acc);
            acc = 0.f; gprev = g;
        }
        acc += G16[(size_t)i * 16 + p];
    }
    atomicAdd(&pooled[gprev * NCLS + p], acc);
}

// ---------------- head: out[g,c] = pooled[g,c]/cnt(g) + bc2[c]; cnt via bsearch on sorted batch ----------------
__global__ __launch_bounds__(256) void k_head16(const float* __restrict__ pooled,
                                                const int* __restrict__ batch,
                                                const float* __restrict__ bc2,
                                                float* __restrict__ out, int n) {
    int idx = blockIdx.x * 256 + threadIdx.x;
    if (idx >= NGRAPH * NCLS) return;
    int g = idx >> 4, c = idx & 15;
    int lo = 0, hi = n;
    while (lo < hi) { int mid = (lo + hi) >> 1; if (batch[mid] < g) lo = mid + 1; else hi = mid; }
    int lb = lo;
    lo = 0; hi = n;
    while (lo < hi) { int mid = (lo + hi) >> 1; if (batch[mid] < g + 1) lo = mid + 1; else hi = mid; }
    float cnt = (float)(lo - lb);
    float inv = 1.0f / fmaxf(cnt, 1.0f);
    out[idx] = pooled[idx] * inv + bc2[c];
}

extern "C" void kernel_launch(void* const* d_in, const int* in_sizes, int n_in,
                              void* d_out, int out_size, void* d_ws, size_t ws_size,
                              hipStream_t stream) {
    const float* x    = (const float*)d_in[0];
    const int*   ei   = (const int*)d_in[1];
    const int*   batch= (const int*)d_in[2];
    const float* W0   = (const float*)d_in[3];
    const float* b0   = (const float*)d_in[4];
    const float* W1   = (const float*)d_in[5];
    const float* b1   = (const float*)d_in[6];
    const float* W2   = (const float*)d_in[7];
    const float* b2   = (const float*)d_in[8];
    const float* Wc   = (const float*)d_in[9];
    const float* bc   = (const float*)d_in[10];
    float* out = (float*)d_out;

    const int N = in_sizes[0] / HID;       // 50000
    const int E = in_sizes[1] / 2;         // 800000
    const int* src = ei;
    const int* dst = ei + E;

    char* p = (char*)d_ws;
    auto alloc = [&](size_t bytes) { void* r = (void*)p; p += (bytes + 255) & ~(size_t)255; return r; };
    int*   counts = (int*)alloc((size_t)N * 4);
    int*   rank   = (int*)alloc((size_t)E * 4);
    int*   csum   = (int*)alloc(256 * 4);
    int*   rowptr = (int*)alloc((size_t)(N + 1) * 4);
    unsigned int* epk = (unsigned int*)alloc((size_t)E * 4);
    float* pooled = (float*)alloc((size_t)NGRAPH * NCLS * 4);
    unsigned short* Tb16 = (unsigned short*)alloc((size_t)N * HID * 2);
    unsigned short* Hb16 = (unsigned short*)alloc((size_t)N * HID * 2);
    float* T16    = (float*)alloc((size_t)N * NCLS * 4);
    float* G16    = (float*)alloc((size_t)N * NCLS * 4);
    unsigned short* Wt   = (unsigned short*)alloc((size_t)2 * HID * HID * 2);
    unsigned short* Wt2c = (unsigned short*)alloc((size_t)NCLS * 128 * 2);
    float* bc2    = (float*)alloc(NCLS * 4);

    const int NB = (N + CHUNK - 1) / CHUNK;

    k_init<<<(N + 255) / 256, 256, 0, stream>>>(counts, pooled, W0, W1, W2, Wc, b2, bc,
                                                Wt, Wt2c, bc2, N);
    k_hist<<<(E + 255) / 256, 256, 0, stream>>>(dst, counts, rank, E);
    k_chunksum<<<NB, 256, 0, stream>>>(counts, csum, N);
    k_rowptr<<<NB, 256, 0, stream>>>(counts, csum, rowptr, N, E);
    k_fill<<<(E + 255) / 256, 256, 0, stream>>>(src, dst, rank, counts, rowptr, epk, E);

    const int gemm_grid = (N + 63) / 64;
    const int agg_grid  = ((size_t)N * 64 + 255) / 256;

    // layer 0
    k_gemm_f32<<<gemm_grid, 256, 0, stream>>>(x, Wt, Tb16, N);
    k_agg<<<agg_grid, 256, 0, stream>>>((const unsigned int*)Tb16, (unsigned int*)Hb16,
                                        rowptr, epk, b0, N);
    // layer 1 (+ folded layer-2 GEMM)
    k_gemm_bf16<<<gemm_grid, 256, 0, stream>>>(Hb16, Wt + 16384, Tb16, N);
    k_agg_fused<<<agg_grid, 256, 0, stream>>>((const unsigned int*)Tb16, T16,
                                              rowptr, epk, b1, Wt2c, N);
    // layer-2 aggregation (no atomics) then run-length pooling
    k_agg16<<<agg_grid, 256, 0, stream>>>(T16, G16, rowptr, epk, N);
    const int pool_blocks = (((N + 63) / 64) * 64 + 255) / 256;
    k_pool16<<<pool_blocks, 256, 0, stream>>>(G16, batch, pooled, N);
    // head
    k_head16<<<(NGRAPH * NCLS + 255) / 256, 256, 0, stream>>>(pooled, batch, bc2, out, N);
}

// Round 12
// 230.147 us; speedup vs baseline: 1.5620x; 1.0232x over previous
//
#include <hip/hip_runtime.h>
#include <hip/hip_bf16.h>
#include <hip/hip_fp16.h>

#define HID 128
#define NCLS 16
#define NGRAPH 64
#define CHUNK 1024

using bf16x8 = __attribute__((ext_vector_type(8))) short;
using f32x4  = __attribute__((ext_vector_type(4))) float;

// round-to-nearest-even f32 -> bf16
__device__ __forceinline__ unsigned int f2bf(float f) {
    unsigned int u = __float_as_uint(f);
    return (u + 0x7FFFu + ((u >> 16) & 1u)) >> 16;
}
__device__ __forceinline__ float bf2f_lo(unsigned int u) { return __uint_as_float(u << 16); }
__device__ __forceinline__ float bf2f_hi(unsigned int u) { return __uint_as_float(u & 0xFFFF0000u); }

// ---------------- init: zero counts/pooled + W0/W1 transpose-bf16 + W2@Wc fold ----------------
__global__ __launch_bounds__(256) void k_init(int* counts, float* pooled,
                                              const float* __restrict__ W0,
                                              const float* __restrict__ W1,
                                              const float* __restrict__ W2,
                                              const float* __restrict__ Wc,
                                              const float* __restrict__ b2,
                                              const float* __restrict__ bcin,
                                              unsigned short* __restrict__ Wt,
                                              unsigned short* __restrict__ Wt2c,
                                              float* __restrict__ bc2, int n) {
    int i = blockIdx.x * 256 + threadIdx.x;
    if (i < n) counts[i] = 0;
    if (i < NGRAPH * NCLS) pooled[i] = 0.0f;
    if (i < 2 * HID * HID) {           // Wt[m][col*128+k] = bf16(W[m][k*128+col])
        int m = i >> 14;
        int r = i & 16383;
        int c = r >> 7, k = r & 127;
        const float* W = (m == 0) ? W0 : W1;
        Wt[i] = (unsigned short)f2bf(W[k * HID + c]);
    }
    if (i < HID * NCLS) {              // Wt2c[c*128+k] = bf16(sum_j W2[k,j]*Wc[j,c])
        int k = i >> 4, c = i & 15;
        float s = 0.f;
        #pragma unroll 8
        for (int j = 0; j < HID; ++j)
            s = fmaf(W2[k * HID + j], Wc[j * NCLS + c], s);
        Wt2c[c * 128 + k] = (unsigned short)f2bf(s);
    }
    if (i < NCLS) {                    // bc2 = b2@Wc + bc
        float s = 0.f;
        for (int j = 0; j < HID; ++j)
            s = fmaf(b2[j], Wc[j * NCLS + i], s);
        bc2[i] = s + bcin[i];
    }
}

// ---------------- degree histogram over dst + per-edge rank ----------------
__global__ __launch_bounds__(256) void k_hist(const int* __restrict__ dst,
                                              int* counts, int* rank, int e) {
    int i = blockIdx.x * 256 + threadIdx.x;
    if (i < e) rank[i] = atomicAdd(&counts[dst[i]], 1);
}

// ---------------- scan step 1: per-chunk sums (coalesced, parallel blocks) ----------------
__global__ __launch_bounds__(256) void k_chunksum(const int* __restrict__ counts,
                                                  int* csum, int n) {
    __shared__ int sdata[256];
    int b = blockIdx.x, t = threadIdx.x;
    int base = b * CHUNK + t * 4;
    int s = 0;
    #pragma unroll
    for (int j = 0; j < 4; ++j) { int i = base + j; if (i < n) s += counts[i]; }
    sdata[t] = s; __syncthreads();
    for (int off = 128; off > 0; off >>= 1) {
        if (t < off) sdata[t] += sdata[t + off];
        __syncthreads();
    }
    if (t == 0) csum[b] = sdata[0];
}

// ---------------- rowptr: per-chunk exclusive scan (chunk offset in-block via wave reduce) ----------------
__global__ __launch_bounds__(256) void k_rowptr(const int* __restrict__ counts,
                                                const int* __restrict__ csum,
                                                int* rowptr, int n, int e) {
    __shared__ int sincl[256];
    __shared__ int s_coff;
    int b = blockIdx.x, t = threadIdx.x;
    if (t < 64) {
        int v = (t < b) ? csum[t] : 0;
        #pragma unroll
        for (int off = 32; off > 0; off >>= 1) v += __shfl_xor(v, off);
        if (t == 0) s_coff = v;
    }
    int base = b * CHUNK + t * 4;
    int v[4]; int s = 0;
    #pragma unroll
    for (int j = 0; j < 4; ++j) { int i = base + j; v[j] = (i < n) ? counts[i] : 0; s += v[j]; }
    sincl[t] = s; __syncthreads();
    for (int off = 1; off < 256; off <<= 1) {
        int x = sincl[t];
        int y = (t >= off) ? sincl[t - off] : 0;
        __syncthreads();
        sincl[t] = x + y;
        __syncthreads();
    }
    int run = s_coff + sincl[t] - s;
    #pragma unroll
    for (int j = 0; j < 4; ++j) {
        int i = base + j;
        if (i < n) { rowptr[i] = run; run += v[j]; }
    }
    if (b == 0 && t == 0) rowptr[n] = e;
}

// ---------------- CSR fill: 4B records {u16 src | fp16 norm}, no atomics ----------------
__global__ __launch_bounds__(256) void k_fill(const int* __restrict__ src,
                                              const int* __restrict__ dst,
                                              const int* __restrict__ rank,
                                              const int* __restrict__ counts,
                                              const int* __restrict__ rowptr,
                                              unsigned int* __restrict__ epk, int e) {
    int i = blockIdx.x * 256 + threadIdx.x;
    if (i >= e) return;
    int s = src[i], d = dst[i];
    int pos = rowptr[d] + rank[i];
    float norm = rsqrtf((float)(counts[s] + 1)) * rsqrtf((float)(counts[d] + 1));
    __half h = __float2half(norm);
    unsigned int hu = (unsigned int)__half_as_ushort(h);
    epk[pos] = (unsigned int)s | (hu << 16);
}

// ---------------- MFMA GEMM (f32 input, layer 0) ----------------
__global__ __launch_bounds__(256) void k_gemm_f32(const float* __restrict__ H,
                                                  const unsigned short* __restrict__ Wt,
                                                  unsigned short* __restrict__ Tb16, int n) {
    __shared__ char ldsA[64 * 256];
    int t = threadIdx.x;
    int cg = t & 31;
    int rg = t >> 5;
    int row0 = blockIdx.x * 64;

    #pragma unroll
    for (int i = 0; i < 8; ++i) {
        int lr = rg + i * 8;
        int r = row0 + lr;
        float4 v = make_float4(0.f, 0.f, 0.f, 0.f);
        if (r < n) v = ((const float4*)H)[(size_t)r * 32 + cg];
        uint2 pk;
        pk.x = f2bf(v.x) | (f2bf(v.y) << 16);
        pk.y = f2bf(v.z) | (f2bf(v.w) << 16);
        int byte = lr * 256 + cg * 8;
        *(uint2*)(ldsA + (byte ^ ((lr & 7) << 4))) = pk;
    }
    __syncthreads();

    int lane = t & 63;
    int w = t >> 6;
    int rsub = lane & 15;
    int kg = lane >> 4;
    int rowIdx = w * 16 + rsub;
    int abase = rowIdx * 256 + kg * 16;
    int aswz = (rowIdx & 7) << 4;

    f32x4 acc[8];
    #pragma unroll
    for (int nt = 0; nt < 8; ++nt) acc[nt] = (f32x4)(0.f);

    #pragma unroll
    for (int kk = 0; kk < 4; ++kk) {
        bf16x8 a = *(const bf16x8*)(ldsA + ((abase + kk * 64) ^ aswz));
        int k0 = kk * 32 + kg * 8;
        #pragma unroll
        for (int nt = 0; nt < 8; ++nt) {
            int col = nt * 16 + rsub;
            bf16x8 b = *(const bf16x8*)(Wt + col * 128 + k0);
            acc[nt] = __builtin_amdgcn_mfma_f32_16x16x32_bf16(a, b, acc[nt], 0, 0, 0);
        }
    }

    // C/D layout: col = lane&15, row = (lane>>4)*4 + reg
    #pragma unroll
    for (int nt = 0; nt < 8; ++nt) {
        #pragma unroll
        for (int j = 0; j < 4; ++j) {
            int row = row0 + w * 16 + kg * 4 + j;
            int col = nt * 16 + rsub;
            if (row < n) Tb16[(size_t)row * 128 + col] = (unsigned short)f2bf(acc[nt][j]);
        }
    }
}

// ---------------- MFMA GEMM (bf16 input, layer 1) ----------------
__global__ __launch_bounds__(256) void k_gemm_bf16(const unsigned short* __restrict__ Hb,
                                                   const unsigned short* __restrict__ Wt,
                                                   unsigned short* __restrict__ Tb16, int n) {
    __shared__ char ldsA[64 * 256];
    int t = threadIdx.x;
    int row0 = blockIdx.x * 64;
    int c16 = t & 15;
    int rbase = t >> 4;

    #pragma unroll
    for (int i = 0; i < 4; ++i) {
        int lr = rbase + i * 16;
        int r = row0 + lr;
        uint4 v = make_uint4(0u, 0u, 0u, 0u);
        if (r < n) v = *(const uint4*)(Hb + (size_t)r * 128 + c16 * 8);
        int byte = lr * 256 + c16 * 16;
        *(uint4*)(ldsA + (byte ^ ((lr & 7) << 4))) = v;
    }
    __syncthreads();

    int lane = t & 63;
    int w = t >> 6;
    int rsub = lane & 15;
    int kg = lane >> 4;
    int rowIdx = w * 16 + rsub;
    int abase = rowIdx * 256 + kg * 16;
    int aswz = (rowIdx & 7) << 4;

    f32x4 acc[8];
    #pragma unroll
    for (int nt = 0; nt < 8; ++nt) acc[nt] = (f32x4)(0.f);

    #pragma unroll
    for (int kk = 0; kk < 4; ++kk) {
        bf16x8 a = *(const bf16x8*)(ldsA + ((abase + kk * 64) ^ aswz));
        int k0 = kk * 32 + kg * 8;
        #pragma unroll
        for (int nt = 0; nt < 8; ++nt) {
            int col = nt * 16 + rsub;
            bf16x8 b = *(const bf16x8*)(Wt + col * 128 + k0);
            acc[nt] = __builtin_amdgcn_mfma_f32_16x16x32_bf16(a, b, acc[nt], 0, 0, 0);
        }
    }

    #pragma unroll
    for (int nt = 0; nt < 8; ++nt) {
        #pragma unroll
        for (int j = 0; j < 4; ++j) {
            int row = row0 + w * 16 + kg * 4 + j;
            int col = nt * 16 + rsub;
            if (row < n) Tb16[(size_t)row * 128 + col] = (unsigned short)f2bf(acc[nt][j]);
        }
    }
}

// ---------------- agg layer 0: bf16 gather, f32 acc -> relu bf16 out ----------------
__global__ __launch_bounds__(256) void k_agg(const unsigned int* __restrict__ Tb,
                                             unsigned int* __restrict__ outB,
                                             const int* __restrict__ rowptr,
                                             const unsigned int* __restrict__ epk,
                                             const float* __restrict__ bias, int n) {
    int wid = (blockIdx.x * 256 + threadIdx.x) >> 6;
    int lane = threadIdx.x & 63;
    if (wid >= n) return;
    float2 b2 = ((const float2*)bias)[lane];
    unsigned int us = Tb[(size_t)wid * 64 + lane];
    int start = rowptr[wid];
    int deg = rowptr[wid + 1] - start;
    float sn = 1.0f / (float)(deg + 1);
    float2 acc;
    acc.x = fmaf(bf2f_lo(us), sn, b2.x);
    acc.y = fmaf(bf2f_hi(us), sn, b2.y);

    for (int j0 = 0; j0 < deg; j0 += 64) {
        int myj = j0 + lane;
        unsigned int rec = 0;
        if (myj < deg) rec = epk[start + myj];
        int m = min(64, deg - j0);
        int jj = 0;
        for (; jj + 16 <= m; jj += 16) {
            unsigned int rr[16], uu[16];
            #pragma unroll
            for (int k = 0; k < 16; ++k) rr[k] = (unsigned int)__shfl((int)rec, jj + k);
            #pragma unroll
            for (int k = 0; k < 16; ++k) uu[k] = Tb[(size_t)(rr[k] & 0xFFFFu) * 64 + lane];
            #pragma unroll
            for (int k = 0; k < 16; ++k) {
                float wk = __half2float(__ushort_as_half((unsigned short)(rr[k] >> 16)));
                acc.x = fmaf(wk, bf2f_lo(uu[k]), acc.x);
                acc.y = fmaf(wk, bf2f_hi(uu[k]), acc.y);
            }
        }
        for (; jj + 4 <= m; jj += 4) {
            unsigned int rr[4], uu[4];
            #pragma unroll
            for (int k = 0; k < 4; ++k) rr[k] = (unsigned int)__shfl((int)rec, jj + k);
            #pragma unroll
            for (int k = 0; k < 4; ++k) uu[k] = Tb[(size_t)(rr[k] & 0xFFFFu) * 64 + lane];
            #pragma unroll
            for (int k = 0; k < 4; ++k) {
                float wk = __half2float(__ushort_as_half((unsigned short)(rr[k] >> 16)));
                acc.x = fmaf(wk, bf2f_lo(uu[k]), acc.x);
                acc.y = fmaf(wk, bf2f_hi(uu[k]), acc.y);
            }
        }
        for (; jj < m; ++jj) {
            unsigned int rj = (unsigned int)__shfl((int)rec, jj);
            unsigned int u = Tb[(size_t)(rj & 0xFFFFu) * 64 + lane];
            float wj = __half2float(__ushort_as_half((unsigned short)(rj >> 16)));
            acc.x = fmaf(wj, bf2f_lo(u), acc.x);
            acc.y = fmaf(wj, bf2f_hi(u), acc.y);
        }
    }

    float rx = fmaxf(acc.x, 0.f), ry = fmaxf(acc.y, 0.f);
    outB[(size_t)wid * 64 + lane] = f2bf(rx) | (f2bf(ry) << 16);
}

// ---------------- agg layer 1 FUSED with 16-wide GEMM (W2@Wc), barrier-free ----------------
// Tail uses intra-wave __shfl of the packed bf16 h-pair (no LDS, no __syncthreads)
// so waves retire independently — avoids block-level max(deg) coupling.
__global__ __launch_bounds__(256) void k_agg_fused(const unsigned int* __restrict__ Tb,
                                                   float* __restrict__ T16,
                                                   const int* __restrict__ rowptr,
                                                   const unsigned int* __restrict__ epk,
                                                   const float* __restrict__ bias,
                                                   const unsigned short* __restrict__ Wt2c,
                                                   int n) {
    int t = threadIdx.x;
    int wid = (blockIdx.x * 256 + t) >> 6;
    int lane = t & 63;
    int c = lane & 15;            // output class
    int half = lane >> 4;         // k-quarter 0..3
    if (wid >= n) return;

    float2 acc;
    float2 b2 = ((const float2*)bias)[lane];
    unsigned int us = Tb[(size_t)wid * 64 + lane];
    int start = rowptr[wid];
    int deg = rowptr[wid + 1] - start;
    float sn = 1.0f / (float)(deg + 1);
    acc.x = fmaf(bf2f_lo(us), sn, b2.x);
    acc.y = fmaf(bf2f_hi(us), sn, b2.y);

    for (int j0 = 0; j0 < deg; j0 += 64) {
        int myj = j0 + lane;
        unsigned int rec = 0;
        if (myj < deg) rec = epk[start + myj];
        int m = min(64, deg - j0);
        int jj = 0;
        for (; jj + 16 <= m; jj += 16) {
            unsigned int rr[16], uu[16];
            #pragma unroll
            for (int k = 0; k < 16; ++k) rr[k] = (unsigned int)__shfl((int)rec, jj + k);
            #pragma unroll
            for (int k = 0; k < 16; ++k) uu[k] = Tb[(size_t)(rr[k] & 0xFFFFu) * 64 + lane];
            #pragma unroll
            for (int k = 0; k < 16; ++k) {
                float wk = __half2float(__ushort_as_half((unsigned short)(rr[k] >> 16)));
                acc.x = fmaf(wk, bf2f_lo(uu[k]), acc.x);
                acc.y = fmaf(wk, bf2f_hi(uu[k]), acc.y);
            }
        }
        for (; jj + 4 <= m; jj += 4) {
            unsigned int rr[4], uu[4];
            #pragma unroll
            for (int k = 0; k < 4; ++k) rr[k] = (unsigned int)__shfl((int)rec, jj + k);
            #pragma unroll
            for (int k = 0; k < 4; ++k) uu[k] = Tb[(size_t)(rr[k] & 0xFFFFu) * 64 + lane];
            #pragma unroll
            for (int k = 0; k < 4; ++k) {
                float wk = __half2float(__ushort_as_half((unsigned short)(rr[k] >> 16)));
                acc.x = fmaf(wk, bf2f_lo(uu[k]), acc.x);
                acc.y = fmaf(wk, bf2f_hi(uu[k]), acc.y);
            }
        }
        for (; jj < m; ++jj) {
            unsigned int rj = (unsigned int)__shfl((int)rec, jj);
            unsigned int u = Tb[(size_t)(rj & 0xFFFFu) * 64 + lane];
            float wj = __half2float(__ushort_as_half((unsigned short)(rj >> 16)));
            acc.x = fmaf(wj, bf2f_lo(u), acc.x);
            acc.y = fmaf(wj, bf2f_hi(u), acc.y);
        }
    }

    // relu + bf16-round (same values the unfused path stored)
    float rx = fmaxf(acc.x, 0.f), ry = fmaxf(acc.y, 0.f);
    unsigned int hv = f2bf(rx) | (f2bf(ry) << 16);

    // load W2c slice (64B contiguous per lane)
    const uint4* wq = (const uint4*)((const unsigned int*)Wt2c + (c * 64 + half * 16));
    uint4 wv0 = wq[0], wv1 = wq[1], wv2 = wq[2], wv3 = wq[3];

    // intra-wave dot: h-pairs live in lanes half*16 + kk
    float part = 0.f;
    #pragma unroll
    for (int kk = 0; kk < 4; ++kk) {
        unsigned int hu = (unsigned int)__shfl((int)hv, half * 16 + kk);
        unsigned int wu = (&wv0.x)[kk];
        part = fmaf(bf2f_lo(hu), bf2f_lo(wu), part);
        part = fmaf(bf2f_hi(hu), bf2f_hi(wu), part);
    }
    #pragma unroll
    for (int kk = 0; kk < 4; ++kk) {
        unsigned int hu = (unsigned int)__shfl((int)hv, half * 16 + 4 + kk);
        unsigned int wu = (&wv1.x)[kk];
        part = fmaf(bf2f_lo(hu), bf2f_lo(wu), part);
        part = fmaf(bf2f_hi(hu), bf2f_hi(wu), part);
    }
    #pragma unroll
    for (int kk = 0; kk < 4; ++kk) {
        unsigned int hu = (unsigned int)__shfl((int)hv, half * 16 + 8 + kk);
        unsigned int wu = (&wv2.x)[kk];
        part = fmaf(bf2f_lo(hu), bf2f_lo(wu), part);
        part = fmaf(bf2f_hi(hu), bf2f_hi(wu), part);
    }
    #pragma unroll
    for (int kk = 0; kk < 4; ++kk) {
        unsigned int hu = (unsigned int)__shfl((int)hv, half * 16 + 12 + kk);
        unsigned int wu = (&wv3.x)[kk];
        part = fmaf(bf2f_lo(hu), bf2f_lo(wu), part);
        part = fmaf(bf2f_hi(hu), bf2f_hi(wu), part);
    }
    part += __shfl_xor(part, 16);
    part += __shfl_xor(part, 32);

    if (half == 0) T16[(size_t)wid * 16 + c] = part;
}

// ---------------- agg16: gather T16 (L2-resident 64B rows) -> G16, no atomics ----------------
__global__ __launch_bounds__(256) void k_agg16(const float* __restrict__ T16,
                                               float* __restrict__ G16,
                                               const int* __restrict__ rowptr,
                                               const unsigned int* __restrict__ epk, int n) {
    int wid = (blockIdx.x * 256 + threadIdx.x) >> 6;
    int lane = threadIdx.x & 63;
    if (wid >= n) return;
    int p = lane & 15;
    int q = lane >> 4;
    int start = rowptr[wid];
    int deg = rowptr[wid + 1] - start;

    float acc = 0.f;
    if (q == 0) {
        float sn = 1.0f / (float)(deg + 1);
        acc = T16[(size_t)wid * 16 + p] * sn;
    }

    for (int j0 = 0; j0 < deg; j0 += 64) {
        int myj = j0 + lane;
        unsigned int rec = 0;
        if (myj < deg) rec = epk[start + myj];
        int m = min(64, deg - j0);
        int mg = (m - q + 3) >> 2;
        int jj = 0;
        for (; jj + 8 <= mg; jj += 8) {
            unsigned int rr[8]; float uu[8];
            #pragma unroll
            for (int k = 0; k < 8; ++k) rr[k] = (unsigned int)__shfl((int)rec, 4 * (jj + k) + q);
            #pragma unroll
            for (int k = 0; k < 8; ++k) uu[k] = T16[(size_t)(rr[k] & 0xFFFFu) * 16 + p];
            #pragma unroll
            for (int k = 0; k < 8; ++k) {
                float wk = __half2float(__ushort_as_half((unsigned short)(rr[k] >> 16)));
                acc = fmaf(wk, uu[k], acc);
            }
        }
        for (; jj < mg; ++jj) {
            unsigned int rj = (unsigned int)__shfl((int)rec, 4 * jj + q);
            float u = T16[(size_t)(rj & 0xFFFFu) * 16 + p];
            float wj = __half2float(__ushort_as_half((unsigned short)(rj >> 16)));
            acc = fmaf(wj, u, acc);
        }
    }

    acc += __shfl_xor(acc, 16);
    acc += __shfl_xor(acc, 32);

    if (q == 0) G16[(size_t)wid * 16 + p] = acc;
}

// ---------------- pool16: run-length segment-sum over sorted batch (few atomics) ----------------
__global__ __launch_bounds__(256) void k_pool16(const float* __restrict__ G16,
                                                const int* __restrict__ batch,
                                                float* pooled, int n) {
    int gw = (blockIdx.x * 256 + threadIdx.x) >> 6;
    int lane = threadIdx.x & 63;
    int p = lane & 15;
    int q = lane >> 4;
    int n0 = gw * 64;
    if (n0 >= n) return;
    int n1 = min(n0 + 64, n);
    int i0 = n0 + q;
    if (i0 >= n1) return;
    int gprev = batch[i0];
    float acc = 0.f;
    for (int i = i0; i < n1; i += 4) {
        int g = batch[i];
        if (g != gprev) {               // uniform within the 16-lane subgroup
            atomicAdd(&pooled[gprev * NCLS + p], acc);
            acc = 0.f; gprev = g;
        }
        acc += G16[(size_t)i * 16 + p];
    }
    atomicAdd(&pooled[gprev * NCLS + p], acc);
}

// ---------------- head: out[g,c] = pooled[g,c]/cnt(g) + bc2[c]; cnt via bsearch on sorted batch ----------------
__global__ __launch_bounds__(256) void k_head16(const float* __restrict__ pooled,
                                                const int* __restrict__ batch,
                                                const float* __restrict__ bc2,
                                                float* __restrict__ out, int n) {
    int idx = blockIdx.x * 256 + threadIdx.x;
    if (idx >= NGRAPH * NCLS) return;
    int g = idx >> 4, c = idx & 15;
    int lo = 0, hi = n;
    while (lo < hi) { int mid = (lo + hi) >> 1; if (batch[mid] < g) lo = mid + 1; else hi = mid; }
    int lb = lo;
    lo = 0; hi = n;
    while (lo < hi) { int mid = (lo + hi) >> 1; if (batch[mid] < g + 1) lo = mid + 1; else hi = mid; }
    float cnt = (float)(lo - lb);
    float inv = 1.0f / fmaxf(cnt, 1.0f);
    out[idx] = pooled[idx] * inv + bc2[c];
}

extern "C" void kernel_launch(void* const* d_in, const int* in_sizes, int n_in,
                              void* d_out, int out_size, void* d_ws, size_t ws_size,
                              hipStream_t stream) {
    const float* x    = (const float*)d_in[0];
    const int*   ei   = (const int*)d_in[1];
    const int*   batch= (const int*)d_in[2];
    const float* W0   = (const float*)d_in[3];
    const float* b0   = (const float*)d_in[4];
    const float* W1   = (const float*)d_in[5];
    const float* b1   = (const float*)d_in[6];
    const float* W2   = (const float*)d_in[7];
    const float* b2   = (const float*)d_in[8];
    const float* Wc   = (const float*)d_in[9];
    const float* bc   = (const float*)d_in[10];
    float* out = (float*)d_out;

    const int N = in_sizes[0] / HID;       // 50000
    const int E = in_sizes[1] / 2;         // 800000
    const int* src = ei;
    const int* dst = ei + E;

    char* p = (char*)d_ws;
    auto alloc = [&](size_t bytes) { void* r = (void*)p; p += (bytes + 255) & ~(size_t)255; return r; };
    int*   counts = (int*)alloc((size_t)N * 4);
    int*   rank   = (int*)alloc((size_t)E * 4);
    int*   csum   = (int*)alloc(256 * 4);
    int*   rowptr = (int*)alloc((size_t)(N + 1) * 4);
    unsigned int* epk = (unsigned int*)alloc((size_t)E * 4);
    float* pooled = (float*)alloc((size_t)NGRAPH * NCLS * 4);
    unsigned short* Tb16 = (unsigned short*)alloc((size_t)N * HID * 2);
    unsigned short* Hb16 = (unsigned short*)alloc((size_t)N * HID * 2);
    float* T16    = (float*)alloc((size_t)N * NCLS * 4);
    float* G16    = (float*)alloc((size_t)N * NCLS * 4);
    unsigned short* Wt   = (unsigned short*)alloc((size_t)2 * HID * HID * 2);
    unsigned short* Wt2c = (unsigned short*)alloc((size_t)NCLS * 128 * 2);
    float* bc2    = (float*)alloc(NCLS * 4);

    const int NB = (N + CHUNK - 1) / CHUNK;

    k_init<<<(N + 255) / 256, 256, 0, stream>>>(counts, pooled, W0, W1, W2, Wc, b2, bc,
                                                Wt, Wt2c, bc2, N);
    k_hist<<<(E + 255) / 256, 256, 0, stream>>>(dst, counts, rank, E);
    k_chunksum<<<NB, 256, 0, stream>>>(counts, csum, N);
    k_rowptr<<<NB, 256, 0, stream>>>(counts, csum, rowptr, N, E);
    k_fill<<<(E + 255) / 256, 256, 0, stream>>>(src, dst, rank, counts, rowptr, epk, E);

    const int gemm_grid = (N + 63) / 64;
    const int agg_grid  = ((size_t)N * 64 + 255) / 256;

    // layer 0
    k_gemm_f32<<<gemm_grid, 256, 0, stream>>>(x, Wt, Tb16, N);
    k_agg<<<agg_grid, 256, 0, stream>>>((const unsigned int*)Tb16, (unsigned int*)Hb16,
                                        rowptr, epk, b0, N);
    // layer 1 (+ folded layer-2 GEMM)
    k_gemm_bf16<<<gemm_grid, 256, 0, stream>>>(Hb16, Wt + 16384, Tb16, N);
    k_agg_fused<<<agg_grid, 256, 0, stream>>>((const unsigned int*)Tb16, T16,
                                              rowptr, epk, b1, Wt2c, N);
    // layer-2 aggregation (no atomics) then run-length pooling
    k_agg16<<<agg_grid, 256, 0, stream>>>(T16, G16, rowptr, epk, N);
    const int pool_blocks = (((N + 63) / 64) * 64 + 255) / 256;
    k_pool16<<<pool_blocks, 256, 0, stream>>>(G16, batch, pooled, N);
    // head
    k_head16<<<(NGRAPH * NCLS + 255) / 256, 256, 0, stream>>>(pooled, batch, bc2, out, N);
}

// Round 14
// 228.223 us; speedup vs baseline: 1.5751x; 1.0084x over previous
//
#include <hip/hip_runtime.h>
#include <hip/hip_bf16.h>
#include <hip/hip_fp16.h>

#define HID 128
#define NCLS 16
#define NGRAPH 64
#define CHUNK 1024

using bf16x8 = __attribute__((ext_vector_type(8))) short;
using f32x4  = __attribute__((ext_vector_type(4))) float;

// round-to-nearest-even f32 -> bf16
__device__ __forceinline__ unsigned int f2bf(float f) {
    unsigned int u = __float_as_uint(f);
    return (u + 0x7FFFu + ((u >> 16) & 1u)) >> 16;
}
__device__ __forceinline__ float bf2f_lo(unsigned int u) { return __uint_as_float(u << 16); }
__device__ __forceinline__ float bf2f_hi(unsigned int u) { return __uint_as_float(u & 0xFFFF0000u); }
__device__ __forceinline__ float h2f(unsigned int rec) {
    return __half2float(__ushort_as_half((unsigned short)(rec >> 16)));
}

// ---------------- init: zero counts/pooled + W0/W1 transpose-bf16 + W2@Wc fold ----------------
__global__ __launch_bounds__(256) void k_init(int* counts, float* pooled,
                                              const float* __restrict__ W0,
                                              const float* __restrict__ W1,
                                              const float* __restrict__ W2,
                                              const float* __restrict__ Wc,
                                              const float* __restrict__ b2,
                                              const float* __restrict__ bcin,
                                              unsigned short* __restrict__ Wt,
                                              unsigned short* __restrict__ Wt2c,
                                              float* __restrict__ bc2, int n) {
    int i = blockIdx.x * 256 + threadIdx.x;
    if (i < n) counts[i] = 0;
    if (i < NGRAPH * NCLS) pooled[i] = 0.0f;
    if (i < 2 * HID * HID) {           // Wt[m][col*128+k] = bf16(W[m][k*128+col])
        int m = i >> 14;
        int r = i & 16383;
        int c = r >> 7, k = r & 127;
        const float* W = (m == 0) ? W0 : W1;
        Wt[i] = (unsigned short)f2bf(W[k * HID + c]);
    }
    if (i < HID * NCLS) {              // Wt2c[c*128+k] = bf16(sum_j W2[k,j]*Wc[j,c])
        int k = i >> 4, c = i & 15;
        float s = 0.f;
        #pragma unroll 8
        for (int j = 0; j < HID; ++j)
            s = fmaf(W2[k * HID + j], Wc[j * NCLS + c], s);
        Wt2c[c * 128 + k] = (unsigned short)f2bf(s);
    }
    if (i < NCLS) {                    // bc2 = b2@Wc + bc
        float s = 0.f;
        for (int j = 0; j < HID; ++j)
            s = fmaf(b2[j], Wc[j * NCLS + i], s);
        bc2[i] = s + bcin[i];
    }
}

// ---------------- degree histogram over dst + per-edge rank ----------------
__global__ __launch_bounds__(256) void k_hist(const int* __restrict__ dst,
                                              int* counts, int* rank, int e) {
    int i = blockIdx.x * 256 + threadIdx.x;
    if (i < e) rank[i] = atomicAdd(&counts[dst[i]], 1);
}

// ---------------- scan step 1: per-chunk sums (coalesced, parallel blocks) ----------------
__global__ __launch_bounds__(256) void k_chunksum(const int* __restrict__ counts,
                                                  int* csum, int n) {
    __shared__ int sdata[256];
    int b = blockIdx.x, t = threadIdx.x;
    int base = b * CHUNK + t * 4;
    int s = 0;
    #pragma unroll
    for (int j = 0; j < 4; ++j) { int i = base + j; if (i < n) s += counts[i]; }
    sdata[t] = s; __syncthreads();
    for (int off = 128; off > 0; off >>= 1) {
        if (t < off) sdata[t] += sdata[t + off];
        __syncthreads();
    }
    if (t == 0) csum[b] = sdata[0];
}

// ---------------- rowptr: per-chunk exclusive scan (chunk offset in-block via wave reduce) ----------------
__global__ __launch_bounds__(256) void k_rowptr(const int* __restrict__ counts,
                                                const int* __restrict__ csum,
                                                int* rowptr, int n, int e) {
    __shared__ int sincl[256];
    __shared__ int s_coff;
    int b = blockIdx.x, t = threadIdx.x;
    if (t < 64) {
        int v = (t < b) ? csum[t] : 0;
        #pragma unroll
        for (int off = 32; off > 0; off >>= 1) v += __shfl_xor(v, off);
        if (t == 0) s_coff = v;
    }
    int base = b * CHUNK + t * 4;
    int v[4]; int s = 0;
    #pragma unroll
    for (int j = 0; j < 4; ++j) { int i = base + j; v[j] = (i < n) ? counts[i] : 0; s += v[j]; }
    sincl[t] = s; __syncthreads();
    for (int off = 1; off < 256; off <<= 1) {
        int x = sincl[t];
        int y = (t >= off) ? sincl[t - off] : 0;
        __syncthreads();
        sincl[t] = x + y;
        __syncthreads();
    }
    int run = s_coff + sincl[t] - s;
    #pragma unroll
    for (int j = 0; j < 4; ++j) {
        int i = base + j;
        if (i < n) { rowptr[i] = run; run += v[j]; }
    }
    if (b == 0 && t == 0) rowptr[n] = e;
}

// ---------------- CSR fill: 4B records {u16 src | fp16 norm}, no atomics ----------------
__global__ __launch_bounds__(256) void k_fill(const int* __restrict__ src,
                                              const int* __restrict__ dst,
                                              const int* __restrict__ rank,
                                              const int* __restrict__ counts,
                                              const int* __restrict__ rowptr,
                                              unsigned int* __restrict__ epk, int e) {
    int i = blockIdx.x * 256 + threadIdx.x;
    if (i >= e) return;
    int s = src[i], d = dst[i];
    int pos = rowptr[d] + rank[i];
    float norm = rsqrtf((float)(counts[s] + 1)) * rsqrtf((float)(counts[d] + 1));
    __half h = __float2half(norm);
    unsigned int hu = (unsigned int)__half_as_ushort(h);
    epk[pos] = (unsigned int)s | (hu << 16);
}

// ---------------- MFMA GEMM (f32 input, layer 0) ----------------
__global__ __launch_bounds__(256) void k_gemm_f32(const float* __restrict__ H,
                                                  const unsigned short* __restrict__ Wt,
                                                  unsigned short* __restrict__ Tb16, int n) {
    __shared__ char ldsA[64 * 256];
    int t = threadIdx.x;
    int cg = t & 31;
    int rg = t >> 5;
    int row0 = blockIdx.x * 64;

    #pragma unroll
    for (int i = 0; i < 8; ++i) {
        int lr = rg + i * 8;
        int r = row0 + lr;
        float4 v = make_float4(0.f, 0.f, 0.f, 0.f);
        if (r < n) v = ((const float4*)H)[(size_t)r * 32 + cg];
        uint2 pk;
        pk.x = f2bf(v.x) | (f2bf(v.y) << 16);
        pk.y = f2bf(v.z) | (f2bf(v.w) << 16);
        int byte = lr * 256 + cg * 8;
        *(uint2*)(ldsA + (byte ^ ((lr & 7) << 4))) = pk;
    }
    __syncthreads();

    int lane = t & 63;
    int w = t >> 6;
    int rsub = lane & 15;
    int kg = lane >> 4;
    int rowIdx = w * 16 + rsub;
    int abase = rowIdx * 256 + kg * 16;
    int aswz = (rowIdx & 7) << 4;

    f32x4 acc[8];
    #pragma unroll
    for (int nt = 0; nt < 8; ++nt) acc[nt] = (f32x4)(0.f);

    #pragma unroll
    for (int kk = 0; kk < 4; ++kk) {
        bf16x8 a = *(const bf16x8*)(ldsA + ((abase + kk * 64) ^ aswz));
        int k0 = kk * 32 + kg * 8;
        #pragma unroll
        for (int nt = 0; nt < 8; ++nt) {
            int col = nt * 16 + rsub;
            bf16x8 b = *(const bf16x8*)(Wt + col * 128 + k0);
            acc[nt] = __builtin_amdgcn_mfma_f32_16x16x32_bf16(a, b, acc[nt], 0, 0, 0);
        }
    }

    // C/D layout: col = lane&15, row = (lane>>4)*4 + reg
    #pragma unroll
    for (int nt = 0; nt < 8; ++nt) {
        #pragma unroll
        for (int j = 0; j < 4; ++j) {
            int row = row0 + w * 16 + kg * 4 + j;
            int col = nt * 16 + rsub;
            if (row < n) Tb16[(size_t)row * 128 + col] = (unsigned short)f2bf(acc[nt][j]);
        }
    }
}

// ---------------- MFMA GEMM (bf16 input, layer 1) ----------------
__global__ __launch_bounds__(256) void k_gemm_bf16(const unsigned short* __restrict__ Hb,
                                                   const unsigned short* __restrict__ Wt,
                                                   unsigned short* __restrict__ Tb16, int n) {
    __shared__ char ldsA[64 * 256];
    int t = threadIdx.x;
    int row0 = blockIdx.x * 64;
    int c16 = t & 15;
    int rbase = t >> 4;

    #pragma unroll
    for (int i = 0; i < 4; ++i) {
        int lr = rbase + i * 16;
        int r = row0 + lr;
        uint4 v = make_uint4(0u, 0u, 0u, 0u);
        if (r < n) v = *(const uint4*)(Hb + (size_t)r * 128 + c16 * 8);
        int byte = lr * 256 + c16 * 16;
        *(uint4*)(ldsA + (byte ^ ((lr & 7) << 4))) = v;
    }
    __syncthreads();

    int lane = t & 63;
    int w = t >> 6;
    int rsub = lane & 15;
    int kg = lane >> 4;
    int rowIdx = w * 16 + rsub;
    int abase = rowIdx * 256 + kg * 16;
    int aswz = (rowIdx & 7) << 4;

    f32x4 acc[8];
    #pragma unroll
    for (int nt = 0; nt < 8; ++nt) acc[nt] = (f32x4)(0.f);

    #pragma unroll
    for (int kk = 0; kk < 4; ++kk) {
        bf16x8 a = *(const bf16x8*)(ldsA + ((abase + kk * 64) ^ aswz));
        int k0 = kk * 32 + kg * 8;
        #pragma unroll
        for (int nt = 0; nt < 8; ++nt) {
            int col = nt * 16 + rsub;
            bf16x8 b = *(const bf16x8*)(Wt + col * 128 + k0);
            acc[nt] = __builtin_amdgcn_mfma_f32_16x16x32_bf16(a, b, acc[nt], 0, 0, 0);
        }
    }

    #pragma unroll
    for (int nt = 0; nt < 8; ++nt) {
        #pragma unroll
        for (int j = 0; j < 4; ++j) {
            int row = row0 + w * 16 + kg * 4 + j;
            int col = nt * 16 + rsub;
            if (row < n) Tb16[(size_t)row * 128 + col] = (unsigned short)f2bf(acc[nt][j]);
        }
    }
}

// ---------------- agg layer 0: 16 feature-lanes x 4 edge-groups, uint4 gather ----------------
// UNIFORM trip count: mg = ceil(m/4) for ALL groups. Slots 4*jj+q >= m hit
// lanes whose rec==0 (myj>=deg guard) -> weight h2f(0)==0, contribution 0.
// Every __shfl is full-wave (no divergence, no register-liveness UB).
__global__ __launch_bounds__(256) void k_agg(const uint4* __restrict__ Tb4,
                                             uint4* __restrict__ outB4,
                                             const int* __restrict__ rowptr,
                                             const unsigned int* __restrict__ epk,
                                             const float4* __restrict__ bias4, int n) {
    int wid = (blockIdx.x * 256 + threadIdx.x) >> 6;
    int lane = threadIdx.x & 63;
    if (wid >= n) return;
    int p = lane & 15;
    int q = lane >> 4;
    int start = rowptr[wid];
    int deg = rowptr[wid + 1] - start;

    float2 acc[4];
    #pragma unroll
    for (int i = 0; i < 4; ++i) acc[i] = make_float2(0.f, 0.f);
    if (q == 0) {
        float sn = 1.0f / (float)(deg + 1);
        uint4 us = Tb4[(size_t)wid * 16 + p];
        float4 bA = bias4[p * 2], bB = bias4[p * 2 + 1];
        acc[0].x = fmaf(bf2f_lo(us.x), sn, bA.x);
        acc[0].y = fmaf(bf2f_hi(us.x), sn, bA.y);
        acc[1].x = fmaf(bf2f_lo(us.y), sn, bA.z);
        acc[1].y = fmaf(bf2f_hi(us.y), sn, bA.w);
        acc[2].x = fmaf(bf2f_lo(us.z), sn, bB.x);
        acc[2].y = fmaf(bf2f_hi(us.z), sn, bB.y);
        acc[3].x = fmaf(bf2f_lo(us.w), sn, bB.z);
        acc[3].y = fmaf(bf2f_hi(us.w), sn, bB.w);
    }

    for (int j0 = 0; j0 < deg; j0 += 64) {
        int myj = j0 + lane;
        unsigned int rec = 0;
        if (myj < deg) rec = epk[start + myj];
        int m = min(64, deg - j0);
        int mg = (m + 3) >> 2;              // UNIFORM across all lanes/groups
        int jj = 0;
        for (; jj + 4 <= mg; jj += 4) {
            unsigned int rr[4]; uint4 uu[4];
            #pragma unroll
            for (int k = 0; k < 4; ++k) rr[k] = (unsigned int)__shfl((int)rec, 4 * (jj + k) + q);
            #pragma unroll
            for (int k = 0; k < 4; ++k) uu[k] = Tb4[(size_t)(rr[k] & 0xFFFFu) * 16 + p];
            #pragma unroll
            for (int k = 0; k < 4; ++k) {
                float wk = h2f(rr[k]);
                acc[0].x = fmaf(wk, bf2f_lo(uu[k].x), acc[0].x);
                acc[0].y = fmaf(wk, bf2f_hi(uu[k].x), acc[0].y);
                acc[1].x = fmaf(wk, bf2f_lo(uu[k].y), acc[1].x);
                acc[1].y = fmaf(wk, bf2f_hi(uu[k].y), acc[1].y);
                acc[2].x = fmaf(wk, bf2f_lo(uu[k].z), acc[2].x);
                acc[2].y = fmaf(wk, bf2f_hi(uu[k].z), acc[2].y);
                acc[3].x = fmaf(wk, bf2f_lo(uu[k].w), acc[3].x);
                acc[3].y = fmaf(wk, bf2f_hi(uu[k].w), acc[3].y);
            }
        }
        for (; jj < mg; ++jj) {
            unsigned int rj = (unsigned int)__shfl((int)rec, 4 * jj + q);
            uint4 u = Tb4[(size_t)(rj & 0xFFFFu) * 16 + p];
            float wj = h2f(rj);
            acc[0].x = fmaf(wj, bf2f_lo(u.x), acc[0].x);
            acc[0].y = fmaf(wj, bf2f_hi(u.x), acc[0].y);
            acc[1].x = fmaf(wj, bf2f_lo(u.y), acc[1].x);
            acc[1].y = fmaf(wj, bf2f_hi(u.y), acc[1].y);
            acc[2].x = fmaf(wj, bf2f_lo(u.z), acc[2].x);
            acc[2].y = fmaf(wj, bf2f_hi(u.z), acc[2].y);
            acc[3].x = fmaf(wj, bf2f_lo(u.w), acc[3].x);
            acc[3].y = fmaf(wj, bf2f_hi(u.w), acc[3].y);
        }
    }

    // combine the 4 edge groups (butterfly: all lanes end with the full sum)
    #pragma unroll
    for (int i = 0; i < 4; ++i) {
        acc[i].x += __shfl_xor(acc[i].x, 16); acc[i].y += __shfl_xor(acc[i].y, 16);
        acc[i].x += __shfl_xor(acc[i].x, 32); acc[i].y += __shfl_xor(acc[i].y, 32);
    }

    if (q == 0) {
        uint4 o;
        o.x = f2bf(fmaxf(acc[0].x, 0.f)) | (f2bf(fmaxf(acc[0].y, 0.f)) << 16);
        o.y = f2bf(fmaxf(acc[1].x, 0.f)) | (f2bf(fmaxf(acc[1].y, 0.f)) << 16);
        o.z = f2bf(fmaxf(acc[2].x, 0.f)) | (f2bf(fmaxf(acc[2].y, 0.f)) << 16);
        o.w = f2bf(fmaxf(acc[3].x, 0.f)) | (f2bf(fmaxf(acc[3].y, 0.f)) << 16);
        outB4[(size_t)wid * 16 + p] = o;
    }
}

// ---------------- agg layer 1 FUSED with 16-wide GEMM (W2@Wc), same uniform 16x4 layout ----------------
__global__ __launch_bounds__(256) void k_agg_fused(const uint4* __restrict__ Tb4,
                                                   float* __restrict__ T16,
                                                   const int* __restrict__ rowptr,
                                                   const unsigned int* __restrict__ epk,
                                                   const float4* __restrict__ bias4,
                                                   const unsigned short* __restrict__ Wt2c,
                                                   int n) {
    int wid = (blockIdx.x * 256 + threadIdx.x) >> 6;
    int lane = threadIdx.x & 63;
    if (wid >= n) return;
    int p = lane & 15;
    int q = lane >> 4;
    int start = rowptr[wid];
    int deg = rowptr[wid + 1] - start;

    float2 acc[4];
    #pragma unroll
    for (int i = 0; i < 4; ++i) acc[i] = make_float2(0.f, 0.f);
    if (q == 0) {
        float sn = 1.0f / (float)(deg + 1);
        uint4 us = Tb4[(size_t)wid * 16 + p];
        float4 bA = bias4[p * 2], bB = bias4[p * 2 + 1];
        acc[0].x = fmaf(bf2f_lo(us.x), sn, bA.x);
        acc[0].y = fmaf(bf2f_hi(us.x), sn, bA.y);
        acc[1].x = fmaf(bf2f_lo(us.y), sn, bA.z);
        acc[1].y = fmaf(bf2f_hi(us.y), sn, bA.w);
        acc[2].x = fmaf(bf2f_lo(us.z), sn, bB.x);
        acc[2].y = fmaf(bf2f_hi(us.z), sn, bB.y);
        acc[3].x = fmaf(bf2f_lo(us.w), sn, bB.z);
        acc[3].y = fmaf(bf2f_hi(us.w), sn, bB.w);
    }

    for (int j0 = 0; j0 < deg; j0 += 64) {
        int myj = j0 + lane;
        unsigned int rec = 0;
        if (myj < deg) rec = epk[start + myj];
        int m = min(64, deg - j0);
        int mg = (m + 3) >> 2;              // UNIFORM across all lanes/groups
        int jj = 0;
        for (; jj + 4 <= mg; jj += 4) {
            unsigned int rr[4]; uint4 uu[4];
            #pragma unroll
            for (int k = 0; k < 4; ++k) rr[k] = (unsigned int)__shfl((int)rec, 4 * (jj + k) + q);
            #pragma unroll
            for (int k = 0; k < 4; ++k) uu[k] = Tb4[(size_t)(rr[k] & 0xFFFFu) * 16 + p];
            #pragma unroll
            for (int k = 0; k < 4; ++k) {
                float wk = h2f(rr[k]);
                acc[0].x = fmaf(wk, bf2f_lo(uu[k].x), acc[0].x);
                acc[0].y = fmaf(wk, bf2f_hi(uu[k].x), acc[0].y);
                acc[1].x = fmaf(wk, bf2f_lo(uu[k].y), acc[1].x);
                acc[1].y = fmaf(wk, bf2f_hi(uu[k].y), acc[1].y);
                acc[2].x = fmaf(wk, bf2f_lo(uu[k].z), acc[2].x);
                acc[2].y = fmaf(wk, bf2f_hi(uu[k].z), acc[2].y);
                acc[3].x = fmaf(wk, bf2f_lo(uu[k].w), acc[3].x);
                acc[3].y = fmaf(wk, bf2f_hi(uu[k].w), acc[3].y);
            }
        }
        for (; jj < mg; ++jj) {
            unsigned int rj = (unsigned int)__shfl((int)rec, 4 * jj + q);
            uint4 u = Tb4[(size_t)(rj & 0xFFFFu) * 16 + p];
            float wj = h2f(rj);
            acc[0].x = fmaf(wj, bf2f_lo(u.x), acc[0].x);
            acc[0].y = fmaf(wj, bf2f_hi(u.x), acc[0].y);
            acc[1].x = fmaf(wj, bf2f_lo(u.y), acc[1].x);
            acc[1].y = fmaf(wj, bf2f_hi(u.y), acc[1].y);
            acc[2].x = fmaf(wj, bf2f_lo(u.z), acc[2].x);
            acc[2].y = fmaf(wj, bf2f_hi(u.z), acc[2].y);
            acc[3].x = fmaf(wj, bf2f_lo(u.w), acc[3].x);
            acc[3].y = fmaf(wj, bf2f_hi(u.w), acc[3].y);
        }
    }

    // combine groups — butterfly leaves the FULL h slice in every lane
    #pragma unroll
    for (int i = 0; i < 4; ++i) {
        acc[i].x += __shfl_xor(acc[i].x, 16); acc[i].y += __shfl_xor(acc[i].y, 16);
        acc[i].x += __shfl_xor(acc[i].x, 32); acc[i].y += __shfl_xor(acc[i].y, 32);
    }

    // relu + bf16-pack (identical rounding to unfused path)
    uint4 hv;
    hv.x = f2bf(fmaxf(acc[0].x, 0.f)) | (f2bf(fmaxf(acc[0].y, 0.f)) << 16);
    hv.y = f2bf(fmaxf(acc[1].x, 0.f)) | (f2bf(fmaxf(acc[1].y, 0.f)) << 16);
    hv.z = f2bf(fmaxf(acc[2].x, 0.f)) | (f2bf(fmaxf(acc[2].y, 0.f)) << 16);
    hv.w = f2bf(fmaxf(acc[3].x, 0.f)) | (f2bf(fmaxf(acc[3].y, 0.f)) << 16);

    // dot with W2c: lane (c=p, q) covers p-slices {q, q+4, q+8, q+12}
    // (full-wave shfls; source lanes 0..15 all active)
    int c = p;
    float part = 0.f;
    #pragma unroll
    for (int s = 0; s < 4; ++s) {
        int ps = q + s * 4;
        unsigned int h0 = (unsigned int)__shfl((int)hv.x, ps);
        unsigned int h1 = (unsigned int)__shfl((int)hv.y, ps);
        unsigned int h2 = (unsigned int)__shfl((int)hv.z, ps);
        unsigned int h3 = (unsigned int)__shfl((int)hv.w, ps);
        uint4 wv = ((const uint4*)Wt2c)[c * 16 + ps];
        part = fmaf(bf2f_lo(h0), bf2f_lo(wv.x), part);
        part = fmaf(bf2f_hi(h0), bf2f_hi(wv.x), part);
        part = fmaf(bf2f_lo(h1), bf2f_lo(wv.y), part);
        part = fmaf(bf2f_hi(h1), bf2f_hi(wv.y), part);
        part = fmaf(bf2f_lo(h2), bf2f_lo(wv.z), part);
        part = fmaf(bf2f_hi(h2), bf2f_hi(wv.z), part);
        part = fmaf(bf2f_lo(h3), bf2f_lo(wv.w), part);
        part = fmaf(bf2f_hi(h3), bf2f_hi(wv.w), part);
    }
    part += __shfl_xor(part, 16);
    part += __shfl_xor(part, 32);

    if (q == 0) T16[(size_t)wid * 16 + c] = part;
}

// ---------------- agg16: gather T16 (L2-resident 64B rows) -> G16, uniform trip count ----------------
__global__ __launch_bounds__(256) void k_agg16(const float* __restrict__ T16,
                                               float* __restrict__ G16,
                                               const int* __restrict__ rowptr,
                                               const unsigned int* __restrict__ epk, int n) {
    int wid = (blockIdx.x * 256 + threadIdx.x) >> 6;
    int lane = threadIdx.x & 63;
    if (wid >= n) return;
    int p = lane & 15;
    int q = lane >> 4;
    int start = rowptr[wid];
    int deg = rowptr[wid + 1] - start;

    float acc = 0.f;
    if (q == 0) {
        float sn = 1.0f / (float)(deg + 1);
        acc = T16[(size_t)wid * 16 + p] * sn;
    }

    for (int j0 = 0; j0 < deg; j0 += 64) {
        int myj = j0 + lane;
        unsigned int rec = 0;
        if (myj < deg) rec = epk[start + myj];
        int m = min(64, deg - j0);
        int mg = (m + 3) >> 2;              // UNIFORM across all lanes/groups
        int jj = 0;
        for (; jj + 8 <= mg; jj += 8) {
            unsigned int rr[8]; float uu[8];
            #pragma unroll
            for (int k = 0; k < 8; ++k) rr[k] = (unsigned int)__shfl((int)rec, 4 * (jj + k) + q);
            #pragma unroll
            for (int k = 0; k < 8; ++k) uu[k] = T16[(size_t)(rr[k] & 0xFFFFu) * 16 + p];
            #pragma unroll
            for (int k = 0; k < 8; ++k) acc = fmaf(h2f(rr[k]), uu[k], acc);
        }
        for (; jj < mg; ++jj) {
            unsigned int rj = (unsigned int)__shfl((int)rec, 4 * jj + q);
            float u = T16[(size_t)(rj & 0xFFFFu) * 16 + p];
            acc = fmaf(h2f(rj), u, acc);
        }
    }

    acc += __shfl_xor(acc, 16);
    acc += __shfl_xor(acc, 32);

    if (q == 0) G16[(size_t)wid * 16 + p] = acc;
}

// ---------------- pool16: run-length segment-sum over sorted batch (few atomics) ----------------
__global__ __launch_bounds__(256) void k_pool16(const float* __restrict__ G16,
                                                const int* __restrict__ batch,
                                                float* pooled, int n) {
    int gw = (blockIdx.x * 256 + threadIdx.x) >> 6;
    int lane = threadIdx.x & 63;
    int p = lane & 15;
    int q = lane >> 4;
    int n0 = gw * 64;
    if (n0 >= n) return;
    int n1 = min(n0 + 64, n);
    int i0 = n0 + q;
    if (i0 >= n1) return;
    int gprev = batch[i0];
    float acc = 0.f;
    for (int i = i0; i < n1; i += 4) {
        int g = batch[i];
        if (g != gprev) {               // uniform within the 16-lane subgroup
            atomicAdd(&pooled[gprev * NCLS + p], acc);
            acc = 0.f; gprev = g;
        }
        acc += G16[(size_t)i * 16 + p];
    }
    atomicAdd(&pooled[gprev * NCLS + p], acc);
}

// ---------------- head: out[g,c] = pooled[g,c]/cnt(g) + bc2[c]; cnt via bsearch on sorted batch ----------------
__global__ __launch_bounds__(256) void k_head16(const float* __restrict__ pooled,
                                                const int* __restrict__ batch,
                                                const float* __restrict__ bc2,
                                                float* __restrict__ out, int n) {
    int idx = blockIdx.x * 256 + threadIdx.x;
    if (idx >= NGRAPH * NCLS) return;
    int g = idx >> 4, c = idx & 15;
    int lo = 0, hi = n;
    while (lo < hi) { int mid = (lo + hi) >> 1; if (batch[mid] < g) lo = mid + 1; else hi = mid; }
    int lb = lo;
    lo = 0; hi = n;
    while (lo < hi) { int mid = (lo + hi) >> 1; if (batch[mid] < g + 1) lo = mid + 1; else hi = mid; }
    float cnt = (float)(lo - lb);
    float inv = 1.0f / fmaxf(cnt, 1.0f);
    out[idx] = pooled[idx] * inv + bc2[c];
}

extern "C" void kernel_launch(void* const* d_in, const int* in_sizes, int n_in,
                              void* d_out, int out_size, void* d_ws, size_t ws_size,
                              hipStream_t stream) {
    const float* x    = (const float*)d_in[0];
    const int*   ei   = (const int*)d_in[1];
    const int*   batch= (const int*)d_in[2];
    const float* W0   = (const float*)d_in[3];
    const float* b0   = (const float*)d_in[4];
    const float* W1   = (const float*)d_in[5];
    const float* b1   = (const float*)d_in[6];
    const float* W2   = (const float*)d_in[7];
    const float* b2   = (const float*)d_in[8];
    const float* Wc   = (const float*)d_in[9];
    const float* bc   = (const float*)d_in[10];
    float* out = (float*)d_out;

    const int N = in_sizes[0] / HID;       // 50000
    const int E = in_sizes[1] / 2;         // 800000
    const int* src = ei;
    const int* dst = ei + E;

    char* p = (char*)d_ws;
    auto alloc = [&](size_t bytes) { void* r = (void*)p; p += (bytes + 255) & ~(size_t)255; return r; };
    int*   counts = (int*)alloc((size_t)N * 4);
    int*   rank   = (int*)alloc((size_t)E * 4);
    int*   csum   = (int*)alloc(256 * 4);
    int*   rowptr = (int*)alloc((size_t)(N + 1) * 4);
    unsigned int* epk = (unsigned int*)alloc((size_t)E * 4);
    float* pooled = (float*)alloc((size_t)NGRAPH * NCLS * 4);
    unsigned short* Tb16 = (unsigned short*)alloc((size_t)N * HID * 2);
    unsigned short* Hb16 = (unsigned short*)alloc((size_t)N * HID * 2);
    float* T16    = (float*)alloc((size_t)N * NCLS * 4);
    float* G16    = (float*)alloc((size_t)N * NCLS * 4);
    unsigned short* Wt   = (unsigned short*)alloc((size_t)2 * HID * HID * 2);
    unsigned short* Wt2c = (unsigned short*)alloc((size_t)NCLS * 128 * 2);
    float* bc2    = (float*)alloc(NCLS * 4);

    const int NB = (N + CHUNK - 1) / CHUNK;

    k_init<<<(N + 255) / 256, 256, 0, stream>>>(counts, pooled, W0, W1, W2, Wc, b2, bc,
                                                Wt, Wt2c, bc2, N);
    k_hist<<<(E + 255) / 256, 256, 0, stream>>>(dst, counts, rank, E);
    k_chunksum<<<NB, 256, 0, stream>>>(counts, csum, N);
    k_rowptr<<<NB, 256, 0, stream>>>(counts, csum, rowptr, N, E);
    k_fill<<<(E + 255) / 256, 256, 0, stream>>>(src, dst, rank, counts, rowptr, epk, E);

    const int gemm_grid = (N + 63) / 64;
    const int agg_grid  = ((size_t)N * 64 + 255) / 256;

    // layer 0
    k_gemm_f32<<<gemm_grid, 256, 0, stream>>>(x, Wt, Tb16, N);
    k_agg<<<agg_grid, 256, 0, stream>>>((const uint4*)Tb16, (uint4*)Hb16,
                                        rowptr, epk, (const float4*)b0, N);
    // layer 1 (+ folded layer-2 GEMM)
    k_gemm_bf16<<<gemm_grid, 256, 0, stream>>>(Hb16, Wt + 16384, Tb16, N);
    k_agg_fused<<<agg_grid, 256, 0, stream>>>((const uint4*)Tb16, T16,
                                              rowptr, epk, (const float4*)b1, Wt2c, N);
    // layer-2 aggregation (no atomics) then run-length pooling
    k_agg16<<<agg_grid, 256, 0, stream>>>(T16, G16, rowptr, epk, N);
    const int pool_blocks = (((N + 63) / 64) * 64 + 255) / 256;
    k_pool16<<<pool_blocks, 256, 0, stream>>>(G16, batch, pooled, N);
    // head
    k_head16<<<(NGRAPH * NCLS + 255) / 256, 256, 0, stream>>>(pooled, batch, bc2, out, N);
}